// Round 14
// baseline (1183.226 us; speedup 1.0000x reference)
//
#include <hip/hip_runtime.h>

#define NPTS 8192
#define NB 2

__device__ __forceinline__ float lrelu(float x) { return x > 0.f ? x : 0.2f * x; }
__device__ __forceinline__ float4 lrelu4(float4 a) {
    return make_float4(lrelu(a.x), lrelu(a.y), lrelu(a.z), lrelu(a.w));
}
__device__ __forceinline__ float4 fmax4(float4 a, float4 b) {
    return make_float4(fmaxf(a.x, b.x), fmaxf(a.y, b.y), fmaxf(a.z, b.z), fmaxf(a.w, b.w));
}
__device__ __forceinline__ float4 add4(float4 a, float4 b) {
    return make_float4(a.x + b.x, a.y + b.y, a.z + b.z, a.w + b.w);
}

// ---------------- prep: transpose layer-2 weights into ws (WbT[c][o]) ----------------
__global__ void k_transpose_w(const float* __restrict__ Wb0, const float* __restrict__ Wb1,
                              float* __restrict__ out) {
    int t = blockIdx.x * 256 + threadIdx.x;
    if (t < 16384)      out[t] = Wb0[(t & 127) * 128 + (t >> 7)];
    else if (t < 32768) { int i = t - 16384; out[t] = Wb1[(i & 127) * 128 + (i >> 7)]; }
}

// ---------------- conv_in: feature [B,128,N] -> x0 [B*N,32] + sq0 [B*N], leaky ----------------
__global__ void k_conv_in(const float* __restrict__ f, const float* __restrict__ W,
                          const float* __restrict__ bias, float* __restrict__ out,
                          float* __restrict__ sq) {
    int gid = blockIdx.x * blockDim.x + threadIdx.x;   // over B*N
    int b = gid >> 13, n = gid & (NPTS - 1);
    const float* fb = f + ((size_t)b << 20) + n;       // b*128*8192
    float acc[32];
    #pragma unroll
    for (int o = 0; o < 32; ++o) acc[o] = bias[o];
    #pragma unroll 4
    for (int c = 0; c < 128; ++c) {
        float xc = fb[(size_t)c * NPTS];               // coalesced across lanes
        #pragma unroll
        for (int o = 0; o < 32; ++o) acc[o] += xc * W[o * 128 + c];  // uniform -> s_load
    }
    float s = 0.f;
    float4* op = (float4*)(out + (size_t)gid * 32);
    #pragma unroll
    for (int o4 = 0; o4 < 8; ++o4) {
        float4 v = make_float4(lrelu(acc[o4 * 4]), lrelu(acc[o4 * 4 + 1]),
                               lrelu(acc[o4 * 4 + 2]), lrelu(acc[o4 * 4 + 3]));
        s += v.x * v.x + v.y * v.y + v.z * v.z + v.w * v.w;
        op[o4] = v;
    }
    sq[gid] = s;
}

// ---------------- premix: A = x @ Wa1^T ; Bm = x @ (Wa2-Wa1)^T + ba ----------------
__global__ __launch_bounds__(256, 4) void k_premix(const float* __restrict__ x,
                                                   const float* __restrict__ Wa,
                                                   const float* __restrict__ ba,
                                                   float* __restrict__ A,
                                                   float* __restrict__ Bm) {
    int tid = threadIdx.x;
    int q = tid >> 6;                       // quarter (wave-uniform)
    int p = blockIdx.x * 64 + (tid & 63);   // point over NB*NPTS
    float4 xv[8];
    {
        const float4* xr = (const float4*)(x + (size_t)p * 32);
        #pragma unroll
        for (int u = 0; u < 8; ++u) xv[u] = xr[u];
    }
    const float* W0 = Wa + q * 32 * 64;     // rows q*32..q*32+31
    float acc[32];
    #pragma unroll
    for (int o = 0; o < 32; ++o) acc[o] = 0.f;
    #pragma unroll 2
    for (int c4 = 0; c4 < 8; ++c4) {
        float4 v = xv[c4];
        #pragma unroll
        for (int o = 0; o < 32; ++o) {
            const float* w = W0 + o * 64 + c4 * 4;   // uniform -> s_load
            acc[o] += v.x * w[0] + v.y * w[1] + v.z * w[2] + v.w * w[3];
        }
    }
    {
        float4* op = (float4*)(A + (size_t)p * 128 + q * 32);
        #pragma unroll
        for (int o4 = 0; o4 < 8; ++o4)
            op[o4] = make_float4(acc[o4 * 4], acc[o4 * 4 + 1], acc[o4 * 4 + 2], acc[o4 * 4 + 3]);
    }
    #pragma unroll
    for (int o = 0; o < 32; ++o) acc[o] = ba[q * 32 + o];
    #pragma unroll 2
    for (int c4 = 0; c4 < 8; ++c4) {
        float4 v = xv[c4];
        #pragma unroll
        for (int o = 0; o < 32; ++o) {
            const float* w1 = W0 + o * 64 + c4 * 4;
            const float* w2 = w1 + 32;
            acc[o] += v.x * (w2[0] - w1[0]) + v.y * (w2[1] - w1[1]) +
                      v.z * (w2[2] - w1[2]) + v.w * (w2[3] - w1[3]);
        }
    }
    {
        float4* op = (float4*)(Bm + (size_t)p * 128 + q * 32);
        #pragma unroll
        for (int o4 = 0; o4 < 8; ++o4)
            op[o4] = make_float4(acc[o4 * 4], acc[o4 * 4 + 1], acc[o4 * 4 + 2], acc[o4 * 4 + 3]);
    }
}

// ---------------- kNN candidates v5: scalar j-rows + j-split halves within block ----------------
// 512 threads = 2 halves x 256 points; each half scans JR/2 j's (wave-uniform jbase ->
// s_load path); halves merged in-block via LDS exchange. Buffer rows = max(C, K).
template <int K, int JS, int C>
__global__ __launch_bounds__(512, 4) void k_knn_cand5(const float* __restrict__ x,
                                                      const float* __restrict__ sqg,
                                                      float* __restrict__ cand_d,
                                                      int* __restrict__ cand_i) {
    constexpr int BR = (K > C) ? K : C;      // LDS rows (append + exchange reuse)
    __shared__ float bufd[BR * 512];         // transposed: slot*512 + tid (conflict-free)
    __shared__ int   bufj[BR * 512];
    constexpr int JR = NPTS / JS;            // 512 for JS=16
    constexpr int JH = JR / 2;               // 256 per half
    constexpr int BPB = (NPTS / 256) * JS;   // blocks per batch

    int tid = threadIdx.x;
    int lid = tid & 255;                     // point index within tile
    int half = __builtin_amdgcn_readfirstlane(tid >> 8);   // wave-uniform half id
    int bid = blockIdx.x;
    int b = bid / BPB;
    int r0 = bid - b * BPB;
    int itile = r0 / JS;
    int jseg = r0 - itile * JS;

    const float* xb = x + ((size_t)b * NPTS) * 32;
    const float* sqb = sqg + (size_t)b * NPTS;
    int pt = itile * 256 + lid;

    float4 xi[8];                            // pre-scaled by 2 (folds the -2*dot mul)
    {
        const float4* xrow = (const float4*)(xb + (size_t)pt * 32);
        #pragma unroll
        for (int u = 0; u < 8; ++u) {
            float4 v = xrow[u];
            xi[u] = make_float4(2.f * v.x, 2.f * v.y, 2.f * v.z, 2.f * v.w);
        }
    }
    float bd[K]; int bi[K];                  // sorted ascending, registers
    #pragma unroll
    for (int r = 0; r < K; ++r) { bd[r] = 1e30f; bi[r] = 0; }
    float thr = 1e30f;
    int cnt = 0;

    auto flush = [&]() {
        #pragma unroll
        for (int u = 0; u < C; ++u) {
            float dv = bufd[u * 512 + tid];
            int jv = bufj[u * 512 + tid];
            float dd = (u < cnt) ? dv : 1e30f;   // 1e30 never inserts (strict <)
            int ji = jv;
            #pragma unroll
            for (int r = 0; r < K; ++r) {
                bool c = dd < bd[r];
                float tf = bd[r]; int ti = bi[r];
                bd[r] = c ? dd : bd[r]; bi[r] = c ? ji : bi[r];
                dd = c ? tf : dd;       ji = c ? ti : ji;
            }
        }
        cnt = 0; thr = bd[K - 1];
    };

    int jbase = jseg * JR + half * JH;       // wave-uniform
    #pragma unroll 1
    for (int jj = 0; jj < JH; ++jj) {
        int j = jbase + jj;
        const float* xr = xb + (size_t)j * 32;   // WAVE-UNIFORM address -> s_load
        float xrv[32];
        #pragma unroll
        for (int c = 0; c < 32; ++c) xrv[c] = xr[c];
        float sj = sqb[j];                        // uniform scalar load
        float a0 = 0.f, a1 = 0.f, a2 = 0.f, a3 = 0.f;   // 4 chains for ILP
        #pragma unroll
        for (int c = 0; c < 8; c += 4) {
            a0 += xrv[4*c+0] * xi[c].x + xrv[4*c+1] * xi[c].y + xrv[4*c+2] * xi[c].z + xrv[4*c+3] * xi[c].w;
            a1 += xrv[4*c+4] * xi[c+1].x + xrv[4*c+5] * xi[c+1].y + xrv[4*c+6] * xi[c+1].z + xrv[4*c+7] * xi[c+1].w;
            a2 += xrv[4*c+8] * xi[c+2].x + xrv[4*c+9] * xi[c+2].y + xrv[4*c+10] * xi[c+2].z + xrv[4*c+11] * xi[c+2].w;
            a3 += xrv[4*c+12] * xi[c+3].x + xrv[4*c+13] * xi[c+3].y + xrv[4*c+14] * xi[c+3].z + xrv[4*c+15] * xi[c+3].w;
        }
        float d = sj - ((a0 + a1) + (a2 + a3));   // rank key (sq_i const offset per i)
        // strict < : on distance tie the earlier (lower-index) j stays -> jax tie-break
        if (d < thr) {
            bufd[cnt * 512 + tid] = d;
            bufj[cnt * 512 + tid] = j;
            cnt++;
        }
        if (__any(cnt >= C)) flush();
    }
    flush();
    // in-block merge of the two halves (BR >= K rows available)
    #pragma unroll
    for (int r = 0; r < K; ++r) { bufd[r * 512 + tid] = bd[r]; bufj[r * 512 + tid] = bi[r]; }
    __syncthreads();
    if (half == 0) {
        // insert partner's (higher-j) entries; strict < keeps own (lower-j) on ties.
        #pragma unroll
        for (int r = 0; r < K; ++r) {
            float dd = bufd[r * 512 + 256 + lid];
            int ji = bufj[r * 512 + 256 + lid];
            #pragma unroll
            for (int q = 0; q < K; ++q) {
                bool c = dd < bd[q];
                float tf = bd[q]; int ti = bi[q];
                bd[q] = c ? dd : bd[q]; bi[q] = c ? ji : bi[q];
                dd = c ? tf : dd;       ji = c ? ti : ji;
            }
        }
        size_t base = ((size_t)jseg * (NB * NPTS) + (size_t)b * NPTS + pt) * K;
        #pragma unroll
        for (int r = 0; r < K; ++r) { cand_d[base + r] = bd[r]; cand_i[base + r] = bi[r]; }
    }
}

// ---------------- merge JS candidate lists -> final idx [B*N, K] ----------------
template <int K, int JS>
__global__ void k_knn_merge(const float* __restrict__ cand_d, const int* __restrict__ cand_i,
                            int* __restrict__ idx_out) {
    constexpr int M = JS * K;
    __shared__ float md[64 * (M + 1)];
    __shared__ int   mi[64 * (M + 1)];
    int tid = threadIdx.x;                  // 64 threads
    int pbase = blockIdx.x * 64;
    for (int v = tid; v < 64 * M; v += 64) {
        int s = v / (64 * K);
        int rem = v - s * 64 * K;
        int p = rem / K;
        size_t g = ((size_t)s * (NB * NPTS) + pbase + p) * K + (rem - p * K);
        md[p * (M + 1) + s * K + (rem - p * K)] = cand_d[g];
        mi[p * (M + 1) + s * K + (rem - p * K)] = cand_i[g];
    }
    __syncthreads();
    float* rd = md + tid * (M + 1);
    int* ri = mi + tid * (M + 1);
    int* op = idx_out + (size_t)(pbase + tid) * K;
    for (int r = 0; r < K; ++r) {
        float best = 1e30f; int bj = 0x7fffffff; int bs = 0;
        for (int u = 0; u < M; ++u) {
            float dv = rd[u]; int jv = ri[u];
            if (dv < best || (dv == best && jv < bj)) { best = dv; bj = jv; bs = u; }
        }
        rd[bs] = 1e30f;
        op[r] = bj;
    }
}

// ---------------- EdgeConv v4: register-lean 6x8 / 4x8 output tiles ----------------
template <int K>
__global__ __launch_bounds__(256, 1)
void k_edgeconv4(const int* __restrict__ idx,
                 const float* __restrict__ A, const float* __restrict__ Bm,
                 const float* __restrict__ WbTg, const float* __restrict__ bb,
                 float* __restrict__ y) {
    constexpr int TE = (K == 12) ? 6 : 4;     // edges per thread
    constexpr int EPI = 16 * TE;              // edges per iter: 96 / 64
    constexpr int PI = EPI / K;               // points per iter: 8 / 16
    constexpr int ITERS = 64 / PI;            // 8 / 4
    constexpr int NT = 256;
    constexpr int HS = 132;                   // H1 row stride

    __shared__ __align__(16) float WbT[128 * 128];
    __shared__ __align__(16) float bb_s[128];
    __shared__ __align__(16) float H1[EPI * HS];
    __shared__ __align__(16) float Pm[(K == 12) ? 16 * 128 : 4];

    int tid = threadIdx.x;
    {
        const float4* sb = (const float4*)WbTg;
        float4* db = (float4*)WbT;
        #pragma unroll
        for (int i = 0; i < 16; ++i) db[tid + i * NT] = sb[tid + i * NT];
        if (tid < 128) bb_s[tid] = bb[tid];
    }

    int b = blockIdx.x >> 7;
    int pbase = (blockIdx.x & 127) * 64;
    const int* idxb = idx + ((size_t)b * NPTS) * K;
    const float4* A4 = (const float4*)(A + ((size_t)b * NPTS) * 128);
    const float4* B4 = (const float4*)(Bm + ((size_t)b * NPTS) * 128);
    float* yb = y + ((size_t)b * NPTS) * 128;

    int og = tid & 15;        // 16 out-groups x 8 outputs
    int eg = tid >> 4;        // 16 edge-groups x TE edges
    int ebase = eg * TE;

    for (int it = 0; it < ITERS; ++it) {
        int pt0 = pbase + it * PI;
        #pragma unroll
        for (int r = 0; r < (EPI * 32) / NT; ++r) {
            int u = tid + r * NT;
            int e = u >> 5, c4 = u & 31;
            int p = pt0 + e / K;
            int j = idxb[(size_t)p * K + (e % K)];
            float4 av = A4[(size_t)j * 32 + c4];
            float4 bv = B4[(size_t)p * 32 + c4];
            *(float4*)&H1[e * HS + 4 * c4] = lrelu4(add4(av, bv));
        }
        __syncthreads();
        float4 acc[TE][2];
        {
            float4 blo = *(const float4*)&bb_s[og * 8];
            float4 bhi = *(const float4*)&bb_s[og * 8 + 4];
            #pragma unroll
            for (int e = 0; e < TE; ++e) { acc[e][0] = blo; acc[e][1] = bhi; }
        }
        #pragma unroll 2
        for (int c4 = 0; c4 < 32; ++c4) {
            float4 hv[TE];
            #pragma unroll
            for (int e = 0; e < TE; ++e)
                hv[e] = *(const float4*)&H1[(ebase + e) * HS + 4 * c4];
            #pragma unroll
            for (int j = 0; j < 4; ++j) {
                const float* wr = &WbT[(4 * c4 + j) * 128 + og * 8];
                float4 wlo = *(const float4*)wr;
                float4 whi = *(const float4*)(wr + 4);
                #pragma unroll
                for (int e = 0; e < TE; ++e) {
                    float hc = (j == 0) ? hv[e].x : (j == 1) ? hv[e].y : (j == 2) ? hv[e].z : hv[e].w;
                    acc[e][0].x += hc * wlo.x; acc[e][0].y += hc * wlo.y;
                    acc[e][0].z += hc * wlo.z; acc[e][0].w += hc * wlo.w;
                    acc[e][1].x += hc * whi.x; acc[e][1].y += hc * whi.y;
                    acc[e][1].z += hc * whi.z; acc[e][1].w += hc * whi.w;
                }
            }
        }
        float4 mlo = lrelu4(acc[0][0]), mhi = lrelu4(acc[0][1]);
        #pragma unroll
        for (int e = 1; e < TE; ++e) {
            mlo = fmax4(mlo, lrelu4(acc[e][0]));
            mhi = fmax4(mhi, lrelu4(acc[e][1]));
        }
        if constexpr (K == 4) {
            float4* yp = (float4*)&yb[((size_t)(pt0 + eg)) * 128 + og * 8];
            yp[0] = mlo; yp[1] = mhi;
            __syncthreads();
        } else {
            *(float4*)&Pm[eg * 128 + og * 8] = mlo;
            *(float4*)&Pm[eg * 128 + og * 8 + 4] = mhi;
            __syncthreads();
            #pragma unroll
            for (int r = 0; r < 4; ++r) {
                int u = tid + r * NT;
                int p = u >> 7, o = u & 127;
                yb[((size_t)(pt0 + p)) * 128 + o] =
                    fmaxf(Pm[(2 * p) * 128 + o], Pm[(2 * p + 1) * 128 + o]);
            }
        }
    }
}

// ---------------- conv_mid: y [B*N,128] -> x1 [B*N,32] + sq1 [B*N], leaky ----------------
__global__ void k_conv_mid(const float* __restrict__ xin, const float* __restrict__ W,
                           const float* __restrict__ bias, float* __restrict__ out,
                           float* __restrict__ sq) {
    int gid = blockIdx.x * blockDim.x + threadIdx.x;
    const float4* row = (const float4*)(xin + (size_t)gid * 128);
    float acc[32];
    #pragma unroll
    for (int o = 0; o < 32; ++o) acc[o] = bias[o];
    #pragma unroll 2
    for (int c4 = 0; c4 < 32; ++c4) {
        float4 v = row[c4];
        #pragma unroll
        for (int o = 0; o < 32; ++o) {
            const float* w = W + o * 128 + c4 * 4;   // uniform -> s_load
            acc[o] += v.x * w[0] + v.y * w[1] + v.z * w[2] + v.w * w[3];
        }
    }
    float s = 0.f;
    float4* op = (float4*)(out + (size_t)gid * 32);
    #pragma unroll
    for (int o4 = 0; o4 < 8; ++o4) {
        float4 v = make_float4(lrelu(acc[o4 * 4]), lrelu(acc[o4 * 4 + 1]),
                               lrelu(acc[o4 * 4 + 2]), lrelu(acc[o4 * 4 + 3]));
        s += v.x * v.x + v.y * v.y + v.z * v.z + v.w * v.w;
        op[o4] = v;
    }
    sq[gid] = s;
}

// ---------------- decoder: y1 [B*N,128] -> out [B*N,12] ----------------
__global__ void k_decoder(const float* __restrict__ xin,
                          const float* __restrict__ W0, const float* __restrict__ b0,
                          const float* __restrict__ W1, const float* __restrict__ b1,
                          const float* __restrict__ W2, const float* __restrict__ b2,
                          float* __restrict__ out) {
    int gid = blockIdx.x * blockDim.x + threadIdx.x;
    const float4* row = (const float4*)(xin + (size_t)gid * 128);
    float h0[6];
    #pragma unroll
    for (int o = 0; o < 6; ++o) h0[o] = b0[o];
    #pragma unroll 4
    for (int c4 = 0; c4 < 32; ++c4) {
        float4 v = row[c4];
        #pragma unroll
        for (int o = 0; o < 6; ++o) {
            const float* w = W0 + o * 128 + c4 * 4;
            h0[o] += v.x * w[0] + v.y * w[1] + v.z * w[2] + v.w * w[3];
        }
    }
    #pragma unroll
    for (int o = 0; o < 6; ++o) h0[o] = lrelu(h0[o]);
    float h1[12];
    #pragma unroll
    for (int o = 0; o < 12; ++o) {
        float a = b1[o];
        #pragma unroll
        for (int j = 0; j < 6; ++j) a += W1[o * 6 + j] * h0[j];
        h1[o] = lrelu(a);
    }
    float* op = out + (size_t)gid * 12;
    #pragma unroll
    for (int o = 0; o < 12; ++o) {
        float a = b2[o];
        #pragma unroll
        for (int j = 0; j < 12; ++j) a += W2[o * 12 + j] * h1[j];
        op[o] = a;
    }
}

extern "C" void kernel_launch(void* const* d_in, const int* in_sizes, int n_in,
                              void* d_out, int out_size, void* d_ws, size_t ws_size,
                              hipStream_t stream) {
    const float* feature = (const float*)d_in[0];
    const float* Wc0 = (const float*)d_in[1];
    const float* bc0 = (const float*)d_in[2];
    const float* We0a = (const float*)d_in[3];
    const float* be0a = (const float*)d_in[4];
    const float* We0b = (const float*)d_in[5];
    const float* be0b = (const float*)d_in[6];
    const float* Wc1 = (const float*)d_in[7];
    const float* bc1 = (const float*)d_in[8];
    const float* We1a = (const float*)d_in[9];
    const float* be1a = (const float*)d_in[10];
    const float* We1b = (const float*)d_in[11];
    const float* be1b = (const float*)d_in[12];
    const float* Wd0 = (const float*)d_in[13];
    const float* bd0 = (const float*)d_in[14];
    const float* Wd1 = (const float*)d_in[15];
    const float* bd1 = (const float*)d_in[16];
    const float* Wd2 = (const float*)d_in[17];
    const float* bd2 = (const float*)d_in[18];
    float* out = (float*)d_out;

    float* f = (float*)d_ws;
    // layout (floats), total ~30.7 MB with phase-based aliasing
    float* x0   = f;                       // [0, 524288)
    float* x1   = f + 524288;              // [524288, 1048576)
    int*   idx0 = (int*)(f + 1048576);     // 196608
    int*   idx1 = (int*)(f + 1245184);     // 65536
    float* wT   = f + 1310720;             // 32768 (WbT0 | WbT1)
    float* Zab  = f + 1343488;             // 4194304: A | Bm
    float* Abuf = Zab;                     // 2097152
    float* Bbuf = Zab + 2097152;           // 2097152
    float* Y    = f + 5537792;             // 2097152: y0, later y1
    float* sq0  = f + 7634944;             // 16384
    float* sq1  = f + 7651328;             // 16384 (end 7667712 ~ 30.7 MB)
    // cand0 (JS=16, K=12): 16*16384*12 = 3145728 each; spans Zab+Y (both dead), ends at sq0
    float* c0d  = Zab;                     // [1343488, 4489216)
    int*   c0i  = (int*)(f + 4489216);     // [4489216, 7634944)
    // cand1 (JS=16, K=4): 16*16384*4 = 1048576 each; fits in Zab (dead during kNN1)
    float* c1d  = Zab;                     // 1048576
    int*   c1i  = (int*)(Zab + 1048576);   // ends 3440640 < 5537792
    float* WbT0 = wT;
    float* WbT1 = wT + 16384;

    k_transpose_w<<<128, 256, 0, stream>>>(We0b, We1b, wT);
    k_conv_in<<<64, 256, 0, stream>>>(feature, Wc0, bc0, x0, sq0);
    k_knn_cand5<12, 16, 8><<<1024, 512, 0, stream>>>(x0, sq0, c0d, c0i);
    k_knn_merge<12, 16><<<256, 64, 0, stream>>>(c0d, c0i, idx0);
    k_premix<<<256, 256, 0, stream>>>(x0, We0a, be0a, Abuf, Bbuf);
    k_edgeconv4<12><<<256, 256, 0, stream>>>(idx0, Abuf, Bbuf, WbT0, be0b, Y);
    k_conv_mid<<<64, 256, 0, stream>>>(Y, Wc1, bc1, x1, sq1);
    k_knn_cand5<4, 16, 8><<<1024, 512, 0, stream>>>(x1, sq1, c1d, c1i);
    k_knn_merge<4, 16><<<256, 64, 0, stream>>>(c1d, c1i, idx1);
    k_premix<<<256, 256, 0, stream>>>(x1, We1a, be1a, Abuf, Bbuf);
    k_edgeconv4<4><<<256, 256, 0, stream>>>(idx1, Abuf, Bbuf, WbT1, be1b, Y);
    k_decoder<<<64, 256, 0, stream>>>(Y, Wd0, bd0, Wd1, bd1, Wd2, bd2, out);
}

// Round 15
// 1069.202 us; speedup vs baseline: 1.1066x; 1.1066x over previous
//
#include <hip/hip_runtime.h>

#define NPTS 8192
#define NB 2

__device__ __forceinline__ float lrelu(float x) { return x > 0.f ? x : 0.2f * x; }
__device__ __forceinline__ float4 lrelu4(float4 a) {
    return make_float4(lrelu(a.x), lrelu(a.y), lrelu(a.z), lrelu(a.w));
}
__device__ __forceinline__ float4 fmax4(float4 a, float4 b) {
    return make_float4(fmaxf(a.x, b.x), fmaxf(a.y, b.y), fmaxf(a.z, b.z), fmaxf(a.w, b.w));
}
__device__ __forceinline__ float4 add4(float4 a, float4 b) {
    return make_float4(a.x + b.x, a.y + b.y, a.z + b.z, a.w + b.w);
}

// ---------------- prep: transpose layer-2 weights into ws (WbT[c][o]) ----------------
__global__ void k_transpose_w(const float* __restrict__ Wb0, const float* __restrict__ Wb1,
                              float* __restrict__ out) {
    int t = blockIdx.x * 256 + threadIdx.x;
    if (t < 16384)      out[t] = Wb0[(t & 127) * 128 + (t >> 7)];
    else if (t < 32768) { int i = t - 16384; out[t] = Wb1[(i & 127) * 128 + (i >> 7)]; }
}

// ---------------- conv_in: feature [B,128,N] -> x0 [B*N,32] + sq0 [B*N], leaky ----------------
__global__ void k_conv_in(const float* __restrict__ f, const float* __restrict__ W,
                          const float* __restrict__ bias, float* __restrict__ out,
                          float* __restrict__ sq) {
    int gid = blockIdx.x * blockDim.x + threadIdx.x;   // over B*N
    int b = gid >> 13, n = gid & (NPTS - 1);
    const float* fb = f + ((size_t)b << 20) + n;       // b*128*8192
    float acc[32];
    #pragma unroll
    for (int o = 0; o < 32; ++o) acc[o] = bias[o];
    #pragma unroll 4
    for (int c = 0; c < 128; ++c) {
        float xc = fb[(size_t)c * NPTS];               // coalesced across lanes
        #pragma unroll
        for (int o = 0; o < 32; ++o) acc[o] += xc * W[o * 128 + c];  // uniform -> s_load
    }
    float s = 0.f;
    float4* op = (float4*)(out + (size_t)gid * 32);
    #pragma unroll
    for (int o4 = 0; o4 < 8; ++o4) {
        float4 v = make_float4(lrelu(acc[o4 * 4]), lrelu(acc[o4 * 4 + 1]),
                               lrelu(acc[o4 * 4 + 2]), lrelu(acc[o4 * 4 + 3]));
        s += v.x * v.x + v.y * v.y + v.z * v.z + v.w * v.w;
        op[o4] = v;
    }
    sq[gid] = s;
}

// ---------------- premix: A = x @ Wa1^T ; Bm = x @ (Wa2-Wa1)^T + ba ----------------
__global__ __launch_bounds__(256, 4) void k_premix(const float* __restrict__ x,
                                                   const float* __restrict__ Wa,
                                                   const float* __restrict__ ba,
                                                   float* __restrict__ A,
                                                   float* __restrict__ Bm) {
    int tid = threadIdx.x;
    int q = tid >> 6;                       // quarter (wave-uniform)
    int p = blockIdx.x * 64 + (tid & 63);   // point over NB*NPTS
    float4 xv[8];
    {
        const float4* xr = (const float4*)(x + (size_t)p * 32);
        #pragma unroll
        for (int u = 0; u < 8; ++u) xv[u] = xr[u];
    }
    const float* W0 = Wa + q * 32 * 64;     // rows q*32..q*32+31
    float acc[32];
    #pragma unroll
    for (int o = 0; o < 32; ++o) acc[o] = 0.f;
    #pragma unroll 2
    for (int c4 = 0; c4 < 8; ++c4) {
        float4 v = xv[c4];
        #pragma unroll
        for (int o = 0; o < 32; ++o) {
            const float* w = W0 + o * 64 + c4 * 4;   // uniform -> s_load
            acc[o] += v.x * w[0] + v.y * w[1] + v.z * w[2] + v.w * w[3];
        }
    }
    {
        float4* op = (float4*)(A + (size_t)p * 128 + q * 32);
        #pragma unroll
        for (int o4 = 0; o4 < 8; ++o4)
            op[o4] = make_float4(acc[o4 * 4], acc[o4 * 4 + 1], acc[o4 * 4 + 2], acc[o4 * 4 + 3]);
    }
    #pragma unroll
    for (int o = 0; o < 32; ++o) acc[o] = ba[q * 32 + o];
    #pragma unroll 2
    for (int c4 = 0; c4 < 8; ++c4) {
        float4 v = xv[c4];
        #pragma unroll
        for (int o = 0; o < 32; ++o) {
            const float* w1 = W0 + o * 64 + c4 * 4;
            const float* w2 = w1 + 32;
            acc[o] += v.x * (w2[0] - w1[0]) + v.y * (w2[1] - w1[1]) +
                      v.z * (w2[2] - w1[2]) + v.w * (w2[3] - w1[3]);
        }
    }
    {
        float4* op = (float4*)(Bm + (size_t)p * 128 + q * 32);
        #pragma unroll
        for (int o4 = 0; o4 < 8; ++o4)
            op[o4] = make_float4(acc[o4 * 4], acc[o4 * 4 + 1], acc[o4 * 4 + 2], acc[o4 * 4 + 3]);
    }
}

// ---------------- kNN candidates v6: scalar j-rows, 2-j manual unroll, half-split ----------------
// 512 threads = 2 halves x 256 points; each half scans JR/2 j's with two INLINE
// uniform row buffers (s_load path); ILP hides scalar-load latency under FMAs.
template <int K, int JS, int C>
__global__ __launch_bounds__(512, 4) void k_knn_cand6(const float* __restrict__ x,
                                                      const float* __restrict__ sqg,
                                                      float* __restrict__ cand_d,
                                                      int* __restrict__ cand_i) {
    constexpr int BR = (K > C) ? K : C;      // LDS rows (append + exchange reuse)
    __shared__ float bufd[BR * 512];         // transposed: slot*512 + tid (conflict-free)
    __shared__ int   bufj[BR * 512];
    constexpr int JR = NPTS / JS;            // 1024
    constexpr int JH = JR / 2;               // 512 per half
    constexpr int BPB = (NPTS / 256) * JS;   // 256 blocks per batch

    int tid = threadIdx.x;
    int lid = tid & 255;                     // point index within tile
    int half = __builtin_amdgcn_readfirstlane(tid >> 8);   // wave-uniform half id
    int bid = blockIdx.x;
    int b = bid / BPB;
    int r0b = bid - b * BPB;
    int itile = r0b / JS;
    int jseg = r0b - itile * JS;

    const float* xb = x + ((size_t)b * NPTS) * 32;
    const float* sqb = sqg + (size_t)b * NPTS;
    int pt = itile * 256 + lid;

    float4 xi[8];                            // pre-scaled by 2 (folds the -2*dot mul)
    {
        const float4* xrow = (const float4*)(xb + (size_t)pt * 32);
        #pragma unroll
        for (int u = 0; u < 8; ++u) {
            float4 v = xrow[u];
            xi[u] = make_float4(2.f * v.x, 2.f * v.y, 2.f * v.z, 2.f * v.w);
        }
    }
    float bd[K]; int bi[K];                  // sorted ascending, registers
    #pragma unroll
    for (int r = 0; r < K; ++r) { bd[r] = 1e30f; bi[r] = 0; }
    float thr = 1e30f;
    int cnt = 0;

    auto flush = [&]() {
        #pragma unroll
        for (int u = 0; u < C; ++u) {
            float dv = bufd[u * 512 + tid];
            int jv = bufj[u * 512 + tid];
            float dd = (u < cnt) ? dv : 1e30f;   // 1e30 never inserts (strict <)
            int ji = jv;
            #pragma unroll
            for (int r = 0; r < K; ++r) {
                bool c = dd < bd[r];
                float tf = bd[r]; int ti = bi[r];
                bd[r] = c ? dd : bd[r]; bi[r] = c ? ji : bi[r];
                dd = c ? tf : dd;       ji = c ? ti : ji;
            }
        }
        cnt = 0; thr = bd[K - 1];
    };

    int jbase = jseg * JR + half * JH;       // wave-uniform
    #pragma unroll 1
    for (int jj = 0; jj < JH; jj += 2) {
        int j0 = jbase + jj;
        int j1 = jbase + jj + 1;
        const float* xr0 = xb + (size_t)j0 * 32;   // WAVE-UNIFORM -> s_load
        const float* xr1 = xb + (size_t)j1 * 32;
        float ra[32], rb[32];
        #pragma unroll
        for (int c = 0; c < 32; ++c) ra[c] = xr0[c];
        #pragma unroll
        for (int c = 0; c < 32; ++c) rb[c] = xr1[c];
        float sj0 = sqb[j0];
        float sj1 = sqb[j1];
        float a0 = 0.f, a1 = 0.f, a2 = 0.f, a3 = 0.f;
        #pragma unroll
        for (int c = 0; c < 8; c += 4) {
            a0 += ra[4*c+0] * xi[c].x + ra[4*c+1] * xi[c].y + ra[4*c+2] * xi[c].z + ra[4*c+3] * xi[c].w;
            a1 += ra[4*c+4] * xi[c+1].x + ra[4*c+5] * xi[c+1].y + ra[4*c+6] * xi[c+1].z + ra[4*c+7] * xi[c+1].w;
            a2 += ra[4*c+8] * xi[c+2].x + ra[4*c+9] * xi[c+2].y + ra[4*c+10] * xi[c+2].z + ra[4*c+11] * xi[c+2].w;
            a3 += ra[4*c+12] * xi[c+3].x + ra[4*c+13] * xi[c+3].y + ra[4*c+14] * xi[c+3].z + ra[4*c+15] * xi[c+3].w;
        }
        float e0 = 0.f, e1 = 0.f, e2 = 0.f, e3 = 0.f;
        #pragma unroll
        for (int c = 0; c < 8; c += 4) {
            e0 += rb[4*c+0] * xi[c].x + rb[4*c+1] * xi[c].y + rb[4*c+2] * xi[c].z + rb[4*c+3] * xi[c].w;
            e1 += rb[4*c+4] * xi[c+1].x + rb[4*c+5] * xi[c+1].y + rb[4*c+6] * xi[c+1].z + rb[4*c+7] * xi[c+1].w;
            e2 += rb[4*c+8] * xi[c+2].x + rb[4*c+9] * xi[c+2].y + rb[4*c+10] * xi[c+2].z + rb[4*c+11] * xi[c+2].w;
            e3 += rb[4*c+12] * xi[c+3].x + rb[4*c+13] * xi[c+3].y + rb[4*c+14] * xi[c+3].z + rb[4*c+15] * xi[c+3].w;
        }
        float d0 = sj0 - ((a0 + a1) + (a2 + a3));   // rank keys (sq_i const offset per i)
        float d1 = sj1 - ((e0 + e1) + (e2 + e3));
        // strict < : on distance tie the earlier (lower-index) j stays -> jax tie-break.
        // j0 appended before j1 keeps ascending-j order within the buffer.
        if (d0 < thr) {
            bufd[cnt * 512 + tid] = d0;
            bufj[cnt * 512 + tid] = j0;
            cnt++;
        }
        if (d1 < thr) {
            bufd[cnt * 512 + tid] = d1;
            bufj[cnt * 512 + tid] = j1;
            cnt++;
        }
        if (__any(cnt >= C - 1)) flush();    // headroom: cnt <= C-2 at loop top
    }
    flush();
    // in-block merge of the two halves (BR >= K rows available)
    #pragma unroll
    for (int r = 0; r < K; ++r) { bufd[r * 512 + tid] = bd[r]; bufj[r * 512 + tid] = bi[r]; }
    __syncthreads();
    if (half == 0) {
        // insert partner's (higher-j) entries; strict < keeps own (lower-j) on ties.
        #pragma unroll
        for (int r = 0; r < K; ++r) {
            float dd = bufd[r * 512 + 256 + lid];
            int ji = bufj[r * 512 + 256 + lid];
            #pragma unroll
            for (int q = 0; q < K; ++q) {
                bool c = dd < bd[q];
                float tf = bd[q]; int ti = bi[q];
                bd[q] = c ? dd : bd[q]; bi[q] = c ? ji : bi[q];
                dd = c ? tf : dd;       ji = c ? ti : ji;
            }
        }
        size_t base = ((size_t)jseg * (NB * NPTS) + (size_t)b * NPTS + pt) * K;
        #pragma unroll
        for (int r = 0; r < K; ++r) { cand_d[base + r] = bd[r]; cand_i[base + r] = bi[r]; }
    }
}

// ---------------- merge JS candidate lists -> final idx [B*N, K] ----------------
template <int K, int JS>
__global__ void k_knn_merge(const float* __restrict__ cand_d, const int* __restrict__ cand_i,
                            int* __restrict__ idx_out) {
    constexpr int M = JS * K;
    __shared__ float md[64 * (M + 1)];
    __shared__ int   mi[64 * (M + 1)];
    int tid = threadIdx.x;                  // 64 threads
    int pbase = blockIdx.x * 64;
    for (int v = tid; v < 64 * M; v += 64) {
        int s = v / (64 * K);
        int rem = v - s * 64 * K;
        int p = rem / K;
        size_t g = ((size_t)s * (NB * NPTS) + pbase + p) * K + (rem - p * K);
        md[p * (M + 1) + s * K + (rem - p * K)] = cand_d[g];
        mi[p * (M + 1) + s * K + (rem - p * K)] = cand_i[g];
    }
    __syncthreads();
    float* rd = md + tid * (M + 1);
    int* ri = mi + tid * (M + 1);
    int* op = idx_out + (size_t)(pbase + tid) * K;
    for (int r = 0; r < K; ++r) {
        float best = 1e30f; int bj = 0x7fffffff; int bs = 0;
        for (int u = 0; u < M; ++u) {
            float dv = rd[u]; int jv = ri[u];
            if (dv < best || (dv == best && jv < bj)) { best = dv; bj = jv; bs = u; }
        }
        rd[bs] = 1e30f;
        op[r] = bj;
    }
}

// ---------------- EdgeConv v4: register-lean 6x8 / 4x8 output tiles ----------------
template <int K>
__global__ __launch_bounds__(256, 1)
void k_edgeconv4(const int* __restrict__ idx,
                 const float* __restrict__ A, const float* __restrict__ Bm,
                 const float* __restrict__ WbTg, const float* __restrict__ bb,
                 float* __restrict__ y) {
    constexpr int TE = (K == 12) ? 6 : 4;     // edges per thread
    constexpr int EPI = 16 * TE;              // edges per iter: 96 / 64
    constexpr int PI = EPI / K;               // points per iter: 8 / 16
    constexpr int ITERS = 64 / PI;            // 8 / 4
    constexpr int NT = 256;
    constexpr int HS = 132;                   // H1 row stride

    __shared__ __align__(16) float WbT[128 * 128];
    __shared__ __align__(16) float bb_s[128];
    __shared__ __align__(16) float H1[EPI * HS];
    __shared__ __align__(16) float Pm[(K == 12) ? 16 * 128 : 4];

    int tid = threadIdx.x;
    {
        const float4* sb = (const float4*)WbTg;
        float4* db = (float4*)WbT;
        #pragma unroll
        for (int i = 0; i < 16; ++i) db[tid + i * NT] = sb[tid + i * NT];
        if (tid < 128) bb_s[tid] = bb[tid];
    }

    int b = blockIdx.x >> 7;
    int pbase = (blockIdx.x & 127) * 64;
    const int* idxb = idx + ((size_t)b * NPTS) * K;
    const float4* A4 = (const float4*)(A + ((size_t)b * NPTS) * 128);
    const float4* B4 = (const float4*)(Bm + ((size_t)b * NPTS) * 128);
    float* yb = y + ((size_t)b * NPTS) * 128;

    int og = tid & 15;        // 16 out-groups x 8 outputs
    int eg = tid >> 4;        // 16 edge-groups x TE edges
    int ebase = eg * TE;

    for (int it = 0; it < ITERS; ++it) {
        int pt0 = pbase + it * PI;
        #pragma unroll
        for (int r = 0; r < (EPI * 32) / NT; ++r) {
            int u = tid + r * NT;
            int e = u >> 5, c4 = u & 31;
            int p = pt0 + e / K;
            int j = idxb[(size_t)p * K + (e % K)];
            float4 av = A4[(size_t)j * 32 + c4];
            float4 bv = B4[(size_t)p * 32 + c4];
            *(float4*)&H1[e * HS + 4 * c4] = lrelu4(add4(av, bv));
        }
        __syncthreads();
        float4 acc[TE][2];
        {
            float4 blo = *(const float4*)&bb_s[og * 8];
            float4 bhi = *(const float4*)&bb_s[og * 8 + 4];
            #pragma unroll
            for (int e = 0; e < TE; ++e) { acc[e][0] = blo; acc[e][1] = bhi; }
        }
        #pragma unroll 2
        for (int c4 = 0; c4 < 32; ++c4) {
            float4 hv[TE];
            #pragma unroll
            for (int e = 0; e < TE; ++e)
                hv[e] = *(const float4*)&H1[(ebase + e) * HS + 4 * c4];
            #pragma unroll
            for (int j = 0; j < 4; ++j) {
                const float* wr = &WbT[(4 * c4 + j) * 128 + og * 8];
                float4 wlo = *(const float4*)wr;
                float4 whi = *(const float4*)(wr + 4);
                #pragma unroll
                for (int e = 0; e < TE; ++e) {
                    float hc = (j == 0) ? hv[e].x : (j == 1) ? hv[e].y : (j == 2) ? hv[e].z : hv[e].w;
                    acc[e][0].x += hc * wlo.x; acc[e][0].y += hc * wlo.y;
                    acc[e][0].z += hc * wlo.z; acc[e][0].w += hc * wlo.w;
                    acc[e][1].x += hc * whi.x; acc[e][1].y += hc * whi.y;
                    acc[e][1].z += hc * whi.z; acc[e][1].w += hc * whi.w;
                }
            }
        }
        float4 mlo = lrelu4(acc[0][0]), mhi = lrelu4(acc[0][1]);
        #pragma unroll
        for (int e = 1; e < TE; ++e) {
            mlo = fmax4(mlo, lrelu4(acc[e][0]));
            mhi = fmax4(mhi, lrelu4(acc[e][1]));
        }
        if constexpr (K == 4) {
            float4* yp = (float4*)&yb[((size_t)(pt0 + eg)) * 128 + og * 8];
            yp[0] = mlo; yp[1] = mhi;
            __syncthreads();
        } else {
            *(float4*)&Pm[eg * 128 + og * 8] = mlo;
            *(float4*)&Pm[eg * 128 + og * 8 + 4] = mhi;
            __syncthreads();
            #pragma unroll
            for (int r = 0; r < 4; ++r) {
                int u = tid + r * NT;
                int p = u >> 7, o = u & 127;
                yb[((size_t)(pt0 + p)) * 128 + o] =
                    fmaxf(Pm[(2 * p) * 128 + o], Pm[(2 * p + 1) * 128 + o]);
            }
        }
    }
}

// ---------------- conv_mid: y [B*N,128] -> x1 [B*N,32] + sq1 [B*N], leaky ----------------
__global__ void k_conv_mid(const float* __restrict__ xin, const float* __restrict__ W,
                           const float* __restrict__ bias, float* __restrict__ out,
                           float* __restrict__ sq) {
    int gid = blockIdx.x * blockDim.x + threadIdx.x;
    const float4* row = (const float4*)(xin + (size_t)gid * 128);
    float acc[32];
    #pragma unroll
    for (int o = 0; o < 32; ++o) acc[o] = bias[o];
    #pragma unroll 2
    for (int c4 = 0; c4 < 32; ++c4) {
        float4 v = row[c4];
        #pragma unroll
        for (int o = 0; o < 32; ++o) {
            const float* w = W + o * 128 + c4 * 4;   // uniform -> s_load
            acc[o] += v.x * w[0] + v.y * w[1] + v.z * w[2] + v.w * w[3];
        }
    }
    float s = 0.f;
    float4* op = (float4*)(out + (size_t)gid * 32);
    #pragma unroll
    for (int o4 = 0; o4 < 8; ++o4) {
        float4 v = make_float4(lrelu(acc[o4 * 4]), lrelu(acc[o4 * 4 + 1]),
                               lrelu(acc[o4 * 4 + 2]), lrelu(acc[o4 * 4 + 3]));
        s += v.x * v.x + v.y * v.y + v.z * v.z + v.w * v.w;
        op[o4] = v;
    }
    sq[gid] = s;
}

// ---------------- decoder: y1 [B*N,128] -> out [B*N,12] ----------------
__global__ void k_decoder(const float* __restrict__ xin,
                          const float* __restrict__ W0, const float* __restrict__ b0,
                          const float* __restrict__ W1, const float* __restrict__ b1,
                          const float* __restrict__ W2, const float* __restrict__ b2,
                          float* __restrict__ out) {
    int gid = blockIdx.x * blockDim.x + threadIdx.x;
    const float4* row = (const float4*)(xin + (size_t)gid * 128);
    float h0[6];
    #pragma unroll
    for (int o = 0; o < 6; ++o) h0[o] = b0[o];
    #pragma unroll 4
    for (int c4 = 0; c4 < 32; ++c4) {
        float4 v = row[c4];
        #pragma unroll
        for (int o = 0; o < 6; ++o) {
            const float* w = W0 + o * 128 + c4 * 4;
            h0[o] += v.x * w[0] + v.y * w[1] + v.z * w[2] + v.w * w[3];
        }
    }
    #pragma unroll
    for (int o = 0; o < 6; ++o) h0[o] = lrelu(h0[o]);
    float h1[12];
    #pragma unroll
    for (int o = 0; o < 12; ++o) {
        float a = b1[o];
        #pragma unroll
        for (int j = 0; j < 6; ++j) a += W1[o * 6 + j] * h0[j];
        h1[o] = lrelu(a);
    }
    float* op = out + (size_t)gid * 12;
    #pragma unroll
    for (int o = 0; o < 12; ++o) {
        float a = b2[o];
        #pragma unroll
        for (int j = 0; j < 12; ++j) a += W2[o * 12 + j] * h1[j];
        op[o] = a;
    }
}

extern "C" void kernel_launch(void* const* d_in, const int* in_sizes, int n_in,
                              void* d_out, int out_size, void* d_ws, size_t ws_size,
                              hipStream_t stream) {
    const float* feature = (const float*)d_in[0];
    const float* Wc0 = (const float*)d_in[1];
    const float* bc0 = (const float*)d_in[2];
    const float* We0a = (const float*)d_in[3];
    const float* be0a = (const float*)d_in[4];
    const float* We0b = (const float*)d_in[5];
    const float* be0b = (const float*)d_in[6];
    const float* Wc1 = (const float*)d_in[7];
    const float* bc1 = (const float*)d_in[8];
    const float* We1a = (const float*)d_in[9];
    const float* be1a = (const float*)d_in[10];
    const float* We1b = (const float*)d_in[11];
    const float* be1b = (const float*)d_in[12];
    const float* Wd0 = (const float*)d_in[13];
    const float* bd0 = (const float*)d_in[14];
    const float* Wd1 = (const float*)d_in[15];
    const float* bd1 = (const float*)d_in[16];
    const float* Wd2 = (const float*)d_in[17];
    const float* bd2 = (const float*)d_in[18];
    float* out = (float*)d_out;

    float* f = (float*)d_ws;
    // layout (floats), total ~30.7 MB with phase-based aliasing
    float* x0   = f;                       // [0, 524288)
    float* x1   = f + 524288;              // [524288, 1048576)
    int*   idx0 = (int*)(f + 1048576);     // 196608
    int*   idx1 = (int*)(f + 1245184);     // 65536
    float* wT   = f + 1310720;             // 32768 (WbT0 | WbT1)
    float* Zab  = f + 1343488;             // 4194304: A | Bm
    float* Abuf = Zab;                     // 2097152
    float* Bbuf = Zab + 2097152;           // 2097152
    float* Y    = f + 5537792;             // 2097152: y0, later y1
    float* sq0  = f + 7634944;             // 16384
    float* sq1  = f + 7651328;             // 16384 (end 7667712 ~ 30.7 MB)
    // cand0 aliases Z (dead before premix writes A/Bm): 8*16384*12 = 1572864 each
    float* c0d  = Zab;                     // 1572864
    int*   c0i  = (int*)(Zab + 1572864);   // ends 3145728 < 4194304
    // cand1 aliases Y (y0 dead after conv_mid): 8*16384*4 = 524288 each
    float* c1d  = Y;                       // 524288
    int*   c1i  = (int*)(Y + 524288);      // ends 1048576 < 2097152
    float* WbT0 = wT;
    float* WbT1 = wT + 16384;

    k_transpose_w<<<128, 256, 0, stream>>>(We0b, We1b, wT);
    k_conv_in<<<64, 256, 0, stream>>>(feature, Wc0, bc0, x0, sq0);
    k_knn_cand6<12, 8, 12><<<512, 512, 0, stream>>>(x0, sq0, c0d, c0i);
    k_knn_merge<12, 8><<<256, 64, 0, stream>>>(c0d, c0i, idx0);
    k_premix<<<256, 256, 0, stream>>>(x0, We0a, be0a, Abuf, Bbuf);
    k_edgeconv4<12><<<256, 256, 0, stream>>>(idx0, Abuf, Bbuf, WbT0, be0b, Y);
    k_conv_mid<<<64, 256, 0, stream>>>(Y, Wc1, bc1, x1, sq1);
    k_knn_cand6<4, 8, 8><<<512, 512, 0, stream>>>(x1, sq1, c1d, c1i);
    k_knn_merge<4, 8><<<256, 64, 0, stream>>>(c1d, c1i, idx1);
    k_premix<<<256, 256, 0, stream>>>(x1, We1a, be1a, Abuf, Bbuf);
    k_edgeconv4<4><<<256, 256, 0, stream>>>(idx1, Abuf, Bbuf, WbT1, be1b, Y);
    k_decoder<<<64, 256, 0, stream>>>(Y, Wd0, bd0, Wd1, bd1, Wd2, bd2, out);
}

// Round 17
// 994.356 us; speedup vs baseline: 1.1899x; 1.0753x over previous
//
#include <hip/hip_runtime.h>

#define NPTS 8192
#define NB 2

typedef __attribute__((ext_vector_type(8))) short short8v;   // 8 bf16 (4 VGPRs)
typedef __attribute__((ext_vector_type(4))) float f32x4;

__device__ __forceinline__ float lrelu(float x) { return x > 0.f ? x : 0.2f * x; }
__device__ __forceinline__ float4 lrelu4(float4 a) {
    return make_float4(lrelu(a.x), lrelu(a.y), lrelu(a.z), lrelu(a.w));
}
__device__ __forceinline__ float4 fmax4(float4 a, float4 b) {
    return make_float4(fmaxf(a.x, b.x), fmaxf(a.y, b.y), fmaxf(a.z, b.z), fmaxf(a.w, b.w));
}
__device__ __forceinline__ float4 add4(float4 a, float4 b) {
    return make_float4(a.x + b.x, a.y + b.y, a.z + b.z, a.w + b.w);
}
__device__ __forceinline__ unsigned short f2bf(float f) {     // RNE bf16
    unsigned int u = __float_as_uint(f);
    return (unsigned short)((u + 0x7FFFu + ((u >> 16) & 1u)) >> 16);
}
__device__ __forceinline__ float bf2f(unsigned short h) {
    return __uint_as_float(((unsigned int)h) << 16);
}

// ---------------- prep: transpose layer-2 weights into ws (WbT[c][o]) ----------------
__global__ void k_transpose_w(const float* __restrict__ Wb0, const float* __restrict__ Wb1,
                              float* __restrict__ out) {
    int t = blockIdx.x * 256 + threadIdx.x;
    if (t < 16384)      out[t] = Wb0[(t & 127) * 128 + (t >> 7)];
    else if (t < 32768) { int i = t - 16384; out[t] = Wb1[(i & 127) * 128 + (i >> 7)]; }
}

// 3-way bf16 split of a float4, packed into 2 uints per level
__device__ __forceinline__ void split3(float4 v, unsigned int* hp, unsigned int* mp,
                                       unsigned int* lp) {
    float c[4] = {v.x, v.y, v.z, v.w};
    unsigned short h[4], m[4], l[4];
    #pragma unroll
    for (int i = 0; i < 4; ++i) {
        h[i] = f2bf(c[i]);
        float r1 = c[i] - bf2f(h[i]);
        m[i] = f2bf(r1);
        float r2 = r1 - bf2f(m[i]);
        l[i] = f2bf(r2);
    }
    hp[0] = (unsigned int)h[0] | ((unsigned int)h[1] << 16);
    hp[1] = (unsigned int)h[2] | ((unsigned int)h[3] << 16);
    mp[0] = (unsigned int)m[0] | ((unsigned int)m[1] << 16);
    mp[1] = (unsigned int)m[2] | ((unsigned int)m[3] << 16);
    lp[0] = (unsigned int)l[0] | ((unsigned int)l[1] << 16);
    lp[1] = (unsigned int)l[2] | ((unsigned int)l[3] << 16);
}

// ---------------- conv_in: feature -> x0 fp32 + sq0 + bf16 h/m/l split ----------------
__global__ void k_conv_in(const float* __restrict__ f, const float* __restrict__ W,
                          const float* __restrict__ bias, float* __restrict__ out,
                          float* __restrict__ sq, unsigned short* __restrict__ xh,
                          unsigned short* __restrict__ xm, unsigned short* __restrict__ xl) {
    int gid = blockIdx.x * blockDim.x + threadIdx.x;   // over B*N
    int b = gid >> 13, n = gid & (NPTS - 1);
    const float* fb = f + ((size_t)b << 20) + n;       // b*128*8192
    float acc[32];
    #pragma unroll
    for (int o = 0; o < 32; ++o) acc[o] = bias[o];
    #pragma unroll 4
    for (int c = 0; c < 128; ++c) {
        float xc = fb[(size_t)c * NPTS];               // coalesced across lanes
        #pragma unroll
        for (int o = 0; o < 32; ++o) acc[o] += xc * W[o * 128 + c];  // uniform -> s_load
    }
    float s = 0.f;
    float4* op = (float4*)(out + (size_t)gid * 32);
    unsigned int* hrow = (unsigned int*)(xh + (size_t)gid * 32);
    unsigned int* mrow = (unsigned int*)(xm + (size_t)gid * 32);
    unsigned int* lrow = (unsigned int*)(xl + (size_t)gid * 32);
    #pragma unroll
    for (int o4 = 0; o4 < 8; ++o4) {
        float4 v = make_float4(lrelu(acc[o4 * 4]), lrelu(acc[o4 * 4 + 1]),
                               lrelu(acc[o4 * 4 + 2]), lrelu(acc[o4 * 4 + 3]));
        s += v.x * v.x + v.y * v.y + v.z * v.z + v.w * v.w;
        op[o4] = v;
        unsigned int hp[2], mp[2], lp[2];
        split3(v, hp, mp, lp);
        *(uint2*)(hrow + o4 * 2) = make_uint2(hp[0], hp[1]);
        *(uint2*)(mrow + o4 * 2) = make_uint2(mp[0], mp[1]);
        *(uint2*)(lrow + o4 * 2) = make_uint2(lp[0], lp[1]);
    }
    sq[gid] = s;
}

// ---------------- premix: A = x @ Wa1^T ; Bm = x @ (Wa2-Wa1)^T + ba ----------------
__global__ __launch_bounds__(256, 4) void k_premix(const float* __restrict__ x,
                                                   const float* __restrict__ Wa,
                                                   const float* __restrict__ ba,
                                                   float* __restrict__ A,
                                                   float* __restrict__ Bm) {
    int tid = threadIdx.x;
    int q = tid >> 6;                       // quarter (wave-uniform)
    int p = blockIdx.x * 64 + (tid & 63);   // point over NB*NPTS
    float4 xv[8];
    {
        const float4* xr = (const float4*)(x + (size_t)p * 32);
        #pragma unroll
        for (int u = 0; u < 8; ++u) xv[u] = xr[u];
    }
    const float* W0 = Wa + q * 32 * 64;     // rows q*32..q*32+31
    float acc[32];
    #pragma unroll
    for (int o = 0; o < 32; ++o) acc[o] = 0.f;
    #pragma unroll 2
    for (int c4 = 0; c4 < 8; ++c4) {
        float4 v = xv[c4];
        #pragma unroll
        for (int o = 0; o < 32; ++o) {
            const float* w = W0 + o * 64 + c4 * 4;   // uniform -> s_load
            acc[o] += v.x * w[0] + v.y * w[1] + v.z * w[2] + v.w * w[3];
        }
    }
    {
        float4* op = (float4*)(A + (size_t)p * 128 + q * 32);
        #pragma unroll
        for (int o4 = 0; o4 < 8; ++o4)
            op[o4] = make_float4(acc[o4 * 4], acc[o4 * 4 + 1], acc[o4 * 4 + 2], acc[o4 * 4 + 3]);
    }
    #pragma unroll
    for (int o = 0; o < 32; ++o) acc[o] = ba[q * 32 + o];
    #pragma unroll 2
    for (int c4 = 0; c4 < 8; ++c4) {
        float4 v = xv[c4];
        #pragma unroll
        for (int o = 0; o < 32; ++o) {
            const float* w1 = W0 + o * 64 + c4 * 4;
            const float* w2 = w1 + 32;
            acc[o] += v.x * (w2[0] - w1[0]) + v.y * (w2[1] - w1[1]) +
                      v.z * (w2[2] - w1[2]) + v.w * (w2[3] - w1[3]);
        }
    }
    {
        float4* op = (float4*)(Bm + (size_t)p * 128 + q * 32);
        #pragma unroll
        for (int o4 = 0; o4 < 8; ++o4)
            op[o4] = make_float4(acc[o4 * 4], acc[o4 * 4 + 1], acc[o4 * 4 + 2], acc[o4 * 4 + 3]);
    }
}

// ---------------- kNN via MFMA Gram (bf16 3-way split, 6 terms) + LDS selection ----------------
// Block: 256 threads (4 waves) = 256-point i-tile x 1024-j segment.
// dot = hh' + hm' + mh' + hl' + lh' + mm'  (error ~1e-6 rel, below fp32 ref noise).
// Dl stride 38: MFMA writes uniform 2-way (free), selection reads 2-way (free).
template <int K, int JS, int C>
__global__ __launch_bounds__(256, 2) void k_knn_mfma(const unsigned short* __restrict__ xh,
                                                     const unsigned short* __restrict__ xm,
                                                     const unsigned short* __restrict__ xl,
                                                     const float* __restrict__ sqg,
                                                     float* __restrict__ cand_d,
                                                     int* __restrict__ cand_i) {
    constexpr int JR = NPTS / JS;            // 1024
    constexpr int NCH = JR / 32;             // 32 chunks
    constexpr int BPB = (NPTS / 256) * JS;   // 256 blocks per batch
    constexpr int DS = 38;                   // Dl row stride

    __shared__ float Dl[256 * DS];
    __shared__ float bufd[C * 256];          // transposed append buffer (conflict-free)
    __shared__ int   bufj[C * 256];

    int tid = threadIdx.x;
    int bid = blockIdx.x;
    int b = bid / BPB;
    int r0b = bid - b * BPB;
    int itile = r0b / JS;
    int jseg = r0b - itile * JS;

    const unsigned short* xhb = xh + ((size_t)b * NPTS) * 32;
    const unsigned short* xmb = xm + ((size_t)b * NPTS) * 32;
    const unsigned short* xlb = xl + ((size_t)b * NPTS) * 32;
    const float* sqb = sqg + (size_t)b * NPTS;

    int lane = tid & 63;
    int w = tid >> 6;          // wave 0..3 -> i rows [w*64, w*64+64)
    int g = lane >> 4;         // k-group: k = g*8 + e
    int r15 = lane & 15;

    // A fragments hoisted (constant over the whole j scan): 12 frags = 48 VGPR
    short8v ah[4], am[4], al[4];
    #pragma unroll
    for (int t = 0; t < 4; ++t) {
        size_t ii = (size_t)(itile * 256 + w * 64 + t * 16 + r15);
        ah[t] = *(const short8v*)(xhb + ii * 32 + g * 8);
        am[t] = *(const short8v*)(xmb + ii * 32 + g * 8);
        al[t] = *(const short8v*)(xlb + ii * 32 + g * 8);
    }

    float bd[K]; int bi[K];                  // sorted ascending, registers
    #pragma unroll
    for (int r = 0; r < K; ++r) { bd[r] = 1e30f; bi[r] = 0; }
    float thr = 1e30f;
    int cnt = 0;

    auto flush = [&]() {
        #pragma unroll
        for (int u = 0; u < C; ++u) {
            float dv = bufd[u * 256 + tid];
            int jv = bufj[u * 256 + tid];
            float dd = (u < cnt) ? dv : 1e30f;   // 1e30 never inserts (strict <)
            int ji = jv;
            #pragma unroll
            for (int r = 0; r < K; ++r) {
                bool c = dd < bd[r];
                float tf = bd[r]; int ti = bi[r];
                bd[r] = c ? dd : bd[r]; bi[r] = c ? ji : bi[r];
                dd = c ? tf : dd;       ji = c ? ti : ji;
            }
        }
        cnt = 0; thr = bd[K - 1];
    };

    int jbase = jseg * JR;
    #pragma unroll 1
    for (int ch = 0; ch < NCH; ++ch) {
        int j0 = jbase + ch * 32;
        // B fragments for this chunk (2 j-tiles of 16, 3 levels)
        short8v bh0, bm0, bl0, bh1, bm1, bl1;
        {
            size_t ja = (size_t)(j0 + r15);
            size_t jb = (size_t)(j0 + 16 + r15);
            bh0 = *(const short8v*)(xhb + ja * 32 + g * 8);
            bm0 = *(const short8v*)(xmb + ja * 32 + g * 8);
            bl0 = *(const short8v*)(xlb + ja * 32 + g * 8);
            bh1 = *(const short8v*)(xhb + jb * 32 + g * 8);
            bm1 = *(const short8v*)(xmb + jb * 32 + g * 8);
            bl1 = *(const short8v*)(xlb + jb * 32 + g * 8);
        }
        #pragma unroll
        for (int t = 0; t < 4; ++t) {
            {
                f32x4 acc = {0.f, 0.f, 0.f, 0.f};
                acc = __builtin_amdgcn_mfma_f32_16x16x32_bf16(am[t], bm0, acc, 0, 0, 0);
                acc = __builtin_amdgcn_mfma_f32_16x16x32_bf16(ah[t], bl0, acc, 0, 0, 0);
                acc = __builtin_amdgcn_mfma_f32_16x16x32_bf16(al[t], bh0, acc, 0, 0, 0);
                acc = __builtin_amdgcn_mfma_f32_16x16x32_bf16(ah[t], bm0, acc, 0, 0, 0);
                acc = __builtin_amdgcn_mfma_f32_16x16x32_bf16(am[t], bh0, acc, 0, 0, 0);
                acc = __builtin_amdgcn_mfma_f32_16x16x32_bf16(ah[t], bh0, acc, 0, 0, 0);
                int il = w * 64 + t * 16 + g * 4;
                Dl[(il + 0) * DS + r15] = acc[0];
                Dl[(il + 1) * DS + r15] = acc[1];
                Dl[(il + 2) * DS + r15] = acc[2];
                Dl[(il + 3) * DS + r15] = acc[3];
            }
            {
                f32x4 acc = {0.f, 0.f, 0.f, 0.f};
                acc = __builtin_amdgcn_mfma_f32_16x16x32_bf16(am[t], bm1, acc, 0, 0, 0);
                acc = __builtin_amdgcn_mfma_f32_16x16x32_bf16(ah[t], bl1, acc, 0, 0, 0);
                acc = __builtin_amdgcn_mfma_f32_16x16x32_bf16(al[t], bh1, acc, 0, 0, 0);
                acc = __builtin_amdgcn_mfma_f32_16x16x32_bf16(ah[t], bm1, acc, 0, 0, 0);
                acc = __builtin_amdgcn_mfma_f32_16x16x32_bf16(am[t], bh1, acc, 0, 0, 0);
                acc = __builtin_amdgcn_mfma_f32_16x16x32_bf16(ah[t], bh1, acc, 0, 0, 0);
                int il = w * 64 + t * 16 + g * 4;
                Dl[(il + 0) * DS + 16 + r15] = acc[0];
                Dl[(il + 1) * DS + 16 + r15] = acc[1];
                Dl[(il + 2) * DS + 16 + r15] = acc[2];
                Dl[(il + 3) * DS + 16 + r15] = acc[3];
            }
        }
        __syncthreads();
        // selection: thread tid owns local point i = tid
        #pragma unroll 1
        for (int jj2 = 0; jj2 < 32; ++jj2) {
            int j = j0 + jj2;
            float dotv = Dl[tid * DS + jj2];
            float d = sqb[j] - 2.f * dotv;   // rank key (sq_i const offset per i)
            // strict < : on distance tie the earlier (lower-index) j stays -> jax tie-break
            if (d < thr) {
                bufd[cnt * 256 + tid] = d;
                bufj[cnt * 256 + tid] = j;
                cnt++;
            }
            if (__any(cnt >= C)) flush();
        }
        __syncthreads();
    }
    flush();
    size_t base = ((size_t)jseg * (NB * NPTS) + (size_t)(b * NPTS) + itile * 256 + tid) * K;
    #pragma unroll
    for (int r = 0; r < K; ++r) { cand_d[base + r] = bd[r]; cand_i[base + r] = bi[r]; }
}

// ---------------- merge JS candidate lists -> final idx [B*N, K] ----------------
template <int K, int JS>
__global__ void k_knn_merge(const float* __restrict__ cand_d, const int* __restrict__ cand_i,
                            int* __restrict__ idx_out) {
    constexpr int M = JS * K;
    __shared__ float md[64 * (M + 1)];
    __shared__ int   mi[64 * (M + 1)];
    int tid = threadIdx.x;                  // 64 threads
    int pbase = blockIdx.x * 64;
    for (int v = tid; v < 64 * M; v += 64) {
        int s = v / (64 * K);
        int rem = v - s * 64 * K;
        int p = rem / K;
        size_t g = ((size_t)s * (NB * NPTS) + pbase + p) * K + (rem - p * K);
        md[p * (M + 1) + s * K + (rem - p * K)] = cand_d[g];
        mi[p * (M + 1) + s * K + (rem - p * K)] = cand_i[g];
    }
    __syncthreads();
    float* rd = md + tid * (M + 1);
    int* ri = mi + tid * (M + 1);
    int* op = idx_out + (size_t)(pbase + tid) * K;
    for (int r = 0; r < K; ++r) {
        float best = 1e30f; int bj = 0x7fffffff; int bs = 0;
        for (int u = 0; u < M; ++u) {
            float dv = rd[u]; int jv = ri[u];
            if (dv < best || (dv == best && jv < bj)) { best = dv; bj = jv; bs = u; }
        }
        rd[bs] = 1e30f;
        op[r] = bj;
    }
}

// ---------------- EdgeConv v4: register-lean 6x8 / 4x8 output tiles ----------------
template <int K>
__global__ __launch_bounds__(256, 1)
void k_edgeconv4(const int* __restrict__ idx,
                 const float* __restrict__ A, const float* __restrict__ Bm,
                 const float* __restrict__ WbTg, const float* __restrict__ bb,
                 float* __restrict__ y) {
    constexpr int TE = (K == 12) ? 6 : 4;     // edges per thread
    constexpr int EPI = 16 * TE;              // edges per iter: 96 / 64
    constexpr int PI = EPI / K;               // points per iter: 8 / 16
    constexpr int ITERS = 64 / PI;            // 8 / 4
    constexpr int NT = 256;
    constexpr int HS = 132;                   // H1 row stride

    __shared__ __align__(16) float WbT[128 * 128];
    __shared__ __align__(16) float bb_s[128];
    __shared__ __align__(16) float H1[EPI * HS];
    __shared__ __align__(16) float Pm[(K == 12) ? 16 * 128 : 4];

    int tid = threadIdx.x;
    {
        const float4* sb = (const float4*)WbTg;
        float4* db = (float4*)WbT;
        #pragma unroll
        for (int i = 0; i < 16; ++i) db[tid + i * NT] = sb[tid + i * NT];
        if (tid < 128) bb_s[tid] = bb[tid];
    }

    int b = blockIdx.x >> 7;
    int pbase = (blockIdx.x & 127) * 64;
    const int* idxb = idx + ((size_t)b * NPTS) * K;
    const float4* A4 = (const float4*)(A + ((size_t)b * NPTS) * 128);
    const float4* B4 = (const float4*)(Bm + ((size_t)b * NPTS) * 128);
    float* yb = y + ((size_t)b * NPTS) * 128;

    int og = tid & 15;        // 16 out-groups x 8 outputs
    int eg = tid >> 4;        // 16 edge-groups x TE edges
    int ebase = eg * TE;

    for (int it = 0; it < ITERS; ++it) {
        int pt0 = pbase + it * PI;
        #pragma unroll
        for (int r = 0; r < (EPI * 32) / NT; ++r) {
            int u = tid + r * NT;
            int e = u >> 5, c4 = u & 31;
            int p = pt0 + e / K;
            int j = idxb[(size_t)p * K + (e % K)];
            float4 av = A4[(size_t)j * 32 + c4];
            float4 bv = B4[(size_t)p * 32 + c4];
            *(float4*)&H1[e * HS + 4 * c4] = lrelu4(add4(av, bv));
        }
        __syncthreads();
        float4 acc[TE][2];
        {
            float4 blo = *(const float4*)&bb_s[og * 8];
            float4 bhi = *(const float4*)&bb_s[og * 8 + 4];
            #pragma unroll
            for (int e = 0; e < TE; ++e) { acc[e][0] = blo; acc[e][1] = bhi; }
        }
        #pragma unroll 2
        for (int c4 = 0; c4 < 32; ++c4) {
            float4 hv[TE];
            #pragma unroll
            for (int e = 0; e < TE; ++e)
                hv[e] = *(const float4*)&H1[(ebase + e) * HS + 4 * c4];
            #pragma unroll
            for (int j = 0; j < 4; ++j) {
                const float* wr = &WbT[(4 * c4 + j) * 128 + og * 8];
                float4 wlo = *(const float4*)wr;
                float4 whi = *(const float4*)(wr + 4);
                #pragma unroll
                for (int e = 0; e < TE; ++e) {
                    float hc = (j == 0) ? hv[e].x : (j == 1) ? hv[e].y : (j == 2) ? hv[e].z : hv[e].w;
                    acc[e][0].x += hc * wlo.x; acc[e][0].y += hc * wlo.y;
                    acc[e][0].z += hc * wlo.z; acc[e][0].w += hc * wlo.w;
                    acc[e][1].x += hc * whi.x; acc[e][1].y += hc * whi.y;
                    acc[e][1].z += hc * whi.z; acc[e][1].w += hc * whi.w;
                }
            }
        }
        float4 mlo = lrelu4(acc[0][0]), mhi = lrelu4(acc[0][1]);
        #pragma unroll
        for (int e = 1; e < TE; ++e) {
            mlo = fmax4(mlo, lrelu4(acc[e][0]));
            mhi = fmax4(mhi, lrelu4(acc[e][1]));
        }
        if constexpr (K == 4) {
            float4* yp = (float4*)&yb[((size_t)(pt0 + eg)) * 128 + og * 8];
            yp[0] = mlo; yp[1] = mhi;
            __syncthreads();
        } else {
            *(float4*)&Pm[eg * 128 + og * 8] = mlo;
            *(float4*)&Pm[eg * 128 + og * 8 + 4] = mhi;
            __syncthreads();
            #pragma unroll
            for (int r = 0; r < 4; ++r) {
                int u = tid + r * NT;
                int p = u >> 7, o = u & 127;
                yb[((size_t)(pt0 + p)) * 128 + o] =
                    fmaxf(Pm[(2 * p) * 128 + o], Pm[(2 * p + 1) * 128 + o]);
            }
        }
    }
}

// ---------------- conv_mid: y -> x1 fp32 + sq1 + bf16 h/m/l split ----------------
__global__ void k_conv_mid(const float* __restrict__ xin, const float* __restrict__ W,
                           const float* __restrict__ bias, float* __restrict__ out,
                           float* __restrict__ sq, unsigned short* __restrict__ xh,
                           unsigned short* __restrict__ xm, unsigned short* __restrict__ xl) {
    int gid = blockIdx.x * blockDim.x + threadIdx.x;
    const float4* row = (const float4*)(xin + (size_t)gid * 128);
    float acc[32];
    #pragma unroll
    for (int o = 0; o < 32; ++o) acc[o] = bias[o];
    #pragma unroll 2
    for (int c4 = 0; c4 < 32; ++c4) {
        float4 v = row[c4];
        #pragma unroll
        for (int o = 0; o < 32; ++o) {
            const float* w = W + o * 128 + c4 * 4;   // uniform -> s_load
            acc[o] += v.x * w[0] + v.y * w[1] + v.z * w[2] + v.w * w[3];
        }
    }
    float s = 0.f;
    float4* op = (float4*)(out + (size_t)gid * 32);
    unsigned int* hrow = (unsigned int*)(xh + (size_t)gid * 32);
    unsigned int* mrow = (unsigned int*)(xm + (size_t)gid * 32);
    unsigned int* lrow = (unsigned int*)(xl + (size_t)gid * 32);
    #pragma unroll
    for (int o4 = 0; o4 < 8; ++o4) {
        float4 v = make_float4(lrelu(acc[o4 * 4]), lrelu(acc[o4 * 4 + 1]),
                               lrelu(acc[o4 * 4 + 2]), lrelu(acc[o4 * 4 + 3]));
        s += v.x * v.x + v.y * v.y + v.z * v.z + v.w * v.w;
        op[o4] = v;
        unsigned int hp[2], mp[2], lp[2];
        split3(v, hp, mp, lp);
        *(uint2*)(hrow + o4 * 2) = make_uint2(hp[0], hp[1]);
        *(uint2*)(mrow + o4 * 2) = make_uint2(mp[0], mp[1]);
        *(uint2*)(lrow + o4 * 2) = make_uint2(lp[0], lp[1]);
    }
    sq[gid] = s;
}

// ---------------- decoder: y1 [B*N,128] -> out [B*N,12] ----------------
__global__ void k_decoder(const float* __restrict__ xin,
                          const float* __restrict__ W0, const float* __restrict__ b0,
                          const float* __restrict__ W1, const float* __restrict__ b1,
                          const float* __restrict__ W2, const float* __restrict__ b2,
                          float* __restrict__ out) {
    int gid = blockIdx.x * blockDim.x + threadIdx.x;
    const float4* row = (const float4*)(xin + (size_t)gid * 128);
    float h0[6];
    #pragma unroll
    for (int o = 0; o < 6; ++o) h0[o] = b0[o];
    #pragma unroll 4
    for (int c4 = 0; c4 < 32; ++c4) {
        float4 v = row[c4];
        #pragma unroll
        for (int o = 0; o < 6; ++o) {
            const float* w = W0 + o * 128 + c4 * 4;
            h0[o] += v.x * w[0] + v.y * w[1] + v.z * w[2] + v.w * w[3];
        }
    }
    #pragma unroll
    for (int o = 0; o < 6; ++o) h0[o] = lrelu(h0[o]);
    float h1[12];
    #pragma unroll
    for (int o = 0; o < 12; ++o) {
        float a = b1[o];
        #pragma unroll
        for (int j = 0; j < 6; ++j) a += W1[o * 6 + j] * h0[j];
        h1[o] = lrelu(a);
    }
    float* op = out + (size_t)gid * 12;
    #pragma unroll
    for (int o = 0; o < 12; ++o) {
        float a = b2[o];
        #pragma unroll
        for (int j = 0; j < 12; ++j) a += W2[o * 12 + j] * h1[j];
        op[o] = a;
    }
}

extern "C" void kernel_launch(void* const* d_in, const int* in_sizes, int n_in,
                              void* d_out, int out_size, void* d_ws, size_t ws_size,
                              hipStream_t stream) {
    const float* feature = (const float*)d_in[0];
    const float* Wc0 = (const float*)d_in[1];
    const float* bc0 = (const float*)d_in[2];
    const float* We0a = (const float*)d_in[3];
    const float* be0a = (const float*)d_in[4];
    const float* We0b = (const float*)d_in[5];
    const float* be0b = (const float*)d_in[6];
    const float* Wc1 = (const float*)d_in[7];
    const float* bc1 = (const float*)d_in[8];
    const float* We1a = (const float*)d_in[9];
    const float* be1a = (const float*)d_in[10];
    const float* We1b = (const float*)d_in[11];
    const float* be1b = (const float*)d_in[12];
    const float* Wd0 = (const float*)d_in[13];
    const float* bd0 = (const float*)d_in[14];
    const float* Wd1 = (const float*)d_in[15];
    const float* bd1 = (const float*)d_in[16];
    const float* Wd2 = (const float*)d_in[17];
    const float* bd2 = (const float*)d_in[18];
    float* out = (float*)d_out;

    float* f = (float*)d_ws;
    // layout (floats), total ~30.7 MB with phase-based aliasing
    float* x0   = f;                       // [0, 524288)
    float* x1   = f + 524288;              // [524288, 1048576)
    int*   idx0 = (int*)(f + 1048576);     // 196608
    int*   idx1 = (int*)(f + 1245184);     // 65536
    float* wT   = f + 1310720;             // 32768 (WbT0 | WbT1)
    float* Zab  = f + 1343488;             // 4194304: A | Bm
    float* Abuf = Zab;                     // 2097152
    float* Bbuf = Zab + 2097152;           // 2097152
    float* Y    = f + 5537792;             // 2097152: y0, later y1
    float* sq0  = f + 7634944;             // 16384
    float* sq1  = f + 7651328;             // 16384 (end 7667712 ~ 30.7 MB)
    // cand0 aliases Zab (dead until premix): 8*16384*12 = 1572864 floats each
    float* c0d  = Zab;
    int*   c0i  = (int*)(Zab + 1572864);   // ends 3145728 < 4194304
    // xh0/xm0/xl0 alias Y (y0 written later by edgeconv): 262144 floats each
    unsigned short* xh0 = (unsigned short*)Y;
    unsigned short* xm0 = (unsigned short*)(Y + 262144);
    unsigned short* xl0 = (unsigned short*)(Y + 524288);
    // xh1/xm1/xl1 alias Zab (c0 dead after merge; premix1 writes A/B after knn<4>)
    unsigned short* xh1 = (unsigned short*)Zab;
    unsigned short* xm1 = (unsigned short*)(Zab + 262144);
    unsigned short* xl1 = (unsigned short*)(Zab + 524288);
    // cand1 aliases Y (y0 and splits dead by then): 524288 floats each
    float* c1d  = Y;
    int*   c1i  = (int*)(Y + 524288);      // ends 1048576 < 2097152
    float* WbT0 = wT;
    float* WbT1 = wT + 16384;

    k_transpose_w<<<128, 256, 0, stream>>>(We0b, We1b, wT);
    k_conv_in<<<64, 256, 0, stream>>>(feature, Wc0, bc0, x0, sq0, xh0, xm0, xl0);
    k_knn_mfma<12, 8, 12><<<512, 256, 0, stream>>>(xh0, xm0, xl0, sq0, c0d, c0i);
    k_knn_merge<12, 8><<<256, 64, 0, stream>>>(c0d, c0i, idx0);
    k_premix<<<256, 256, 0, stream>>>(x0, We0a, be0a, Abuf, Bbuf);
    k_edgeconv4<12><<<256, 256, 0, stream>>>(idx0, Abuf, Bbuf, WbT0, be0b, Y);
    k_conv_mid<<<64, 256, 0, stream>>>(Y, Wc1, bc1, x1, sq1, xh1, xm1, xl1);
    k_knn_mfma<4, 8, 8><<<512, 256, 0, stream>>>(xh1, xm1, xl1, sq1, c1d, c1i);
    k_knn_merge<4, 8><<<256, 64, 0, stream>>>(c1d, c1i, idx1);
    k_premix<<<256, 256, 0, stream>>>(x1, We1a, be1a, Abuf, Bbuf);
    k_edgeconv4<4><<<256, 256, 0, stream>>>(idx1, Abuf, Bbuf, WbT1, be1b, Y);
    k_decoder<<<64, 256, 0, stream>>>(Y, Wd0, bd0, Wd1, bd1, Wd2, bd2, out);
}

// Round 18
// 868.521 us; speedup vs baseline: 1.3623x; 1.1449x over previous
//
#include <hip/hip_runtime.h>

#define NPTS 8192
#define NB 2

typedef __attribute__((ext_vector_type(8))) short short8v;   // 8 bf16 (4 VGPRs)
typedef __attribute__((ext_vector_type(4))) float f32x4;

__device__ __forceinline__ float lrelu(float x) { return x > 0.f ? x : 0.2f * x; }
__device__ __forceinline__ float4 lrelu4(float4 a) {
    return make_float4(lrelu(a.x), lrelu(a.y), lrelu(a.z), lrelu(a.w));
}
__device__ __forceinline__ float4 fmax4(float4 a, float4 b) {
    return make_float4(fmaxf(a.x, b.x), fmaxf(a.y, b.y), fmaxf(a.z, b.z), fmaxf(a.w, b.w));
}
__device__ __forceinline__ float4 add4(float4 a, float4 b) {
    return make_float4(a.x + b.x, a.y + b.y, a.z + b.z, a.w + b.w);
}
__device__ __forceinline__ unsigned short f2bf(float f) {     // RNE bf16
    unsigned int u = __float_as_uint(f);
    return (unsigned short)((u + 0x7FFFu + ((u >> 16) & 1u)) >> 16);
}
__device__ __forceinline__ float bf2f(unsigned short h) {
    return __uint_as_float(((unsigned int)h) << 16);
}

// ---------------- prep: transpose layer-2 weights into ws (WbT[c][o]) ----------------
__global__ void k_transpose_w(const float* __restrict__ Wb0, const float* __restrict__ Wb1,
                              float* __restrict__ out) {
    int t = blockIdx.x * 256 + threadIdx.x;
    if (t < 16384)      out[t] = Wb0[(t & 127) * 128 + (t >> 7)];
    else if (t < 32768) { int i = t - 16384; out[t] = Wb1[(i & 127) * 128 + (i >> 7)]; }
}

// 3-way bf16 split of a float4, packed into 2 uints per level
__device__ __forceinline__ void split3(float4 v, unsigned int* hp, unsigned int* mp,
                                       unsigned int* lp) {
    float c[4] = {v.x, v.y, v.z, v.w};
    unsigned short h[4], m[4], l[4];
    #pragma unroll
    for (int i = 0; i < 4; ++i) {
        h[i] = f2bf(c[i]);
        float r1 = c[i] - bf2f(h[i]);
        m[i] = f2bf(r1);
        float r2 = r1 - bf2f(m[i]);
        l[i] = f2bf(r2);
    }
    hp[0] = (unsigned int)h[0] | ((unsigned int)h[1] << 16);
    hp[1] = (unsigned int)h[2] | ((unsigned int)h[3] << 16);
    mp[0] = (unsigned int)m[0] | ((unsigned int)m[1] << 16);
    mp[1] = (unsigned int)m[2] | ((unsigned int)m[3] << 16);
    lp[0] = (unsigned int)l[0] | ((unsigned int)l[1] << 16);
    lp[1] = (unsigned int)l[2] | ((unsigned int)l[3] << 16);
}

// ---------------- conv_in: feature -> x0 fp32 + sq0 + bf16 h/m/l split ----------------
__global__ void k_conv_in(const float* __restrict__ f, const float* __restrict__ W,
                          const float* __restrict__ bias, float* __restrict__ out,
                          float* __restrict__ sq, unsigned short* __restrict__ xh,
                          unsigned short* __restrict__ xm, unsigned short* __restrict__ xl) {
    int gid = blockIdx.x * blockDim.x + threadIdx.x;   // over B*N
    int b = gid >> 13, n = gid & (NPTS - 1);
    const float* fb = f + ((size_t)b << 20) + n;       // b*128*8192
    float acc[32];
    #pragma unroll
    for (int o = 0; o < 32; ++o) acc[o] = bias[o];
    #pragma unroll 4
    for (int c = 0; c < 128; ++c) {
        float xc = fb[(size_t)c * NPTS];               // coalesced across lanes
        #pragma unroll
        for (int o = 0; o < 32; ++o) acc[o] += xc * W[o * 128 + c];  // uniform -> s_load
    }
    float s = 0.f;
    float4* op = (float4*)(out + (size_t)gid * 32);
    unsigned int* hrow = (unsigned int*)(xh + (size_t)gid * 32);
    unsigned int* mrow = (unsigned int*)(xm + (size_t)gid * 32);
    unsigned int* lrow = (unsigned int*)(xl + (size_t)gid * 32);
    #pragma unroll
    for (int o4 = 0; o4 < 8; ++o4) {
        float4 v = make_float4(lrelu(acc[o4 * 4]), lrelu(acc[o4 * 4 + 1]),
                               lrelu(acc[o4 * 4 + 2]), lrelu(acc[o4 * 4 + 3]));
        s += v.x * v.x + v.y * v.y + v.z * v.z + v.w * v.w;
        op[o4] = v;
        unsigned int hp[2], mp[2], lp[2];
        split3(v, hp, mp, lp);
        *(uint2*)(hrow + o4 * 2) = make_uint2(hp[0], hp[1]);
        *(uint2*)(mrow + o4 * 2) = make_uint2(mp[0], mp[1]);
        *(uint2*)(lrow + o4 * 2) = make_uint2(lp[0], lp[1]);
    }
    sq[gid] = s;
}

// ---------------- premix: A = x @ Wa1^T ; Bm = x @ (Wa2-Wa1)^T + ba ----------------
__global__ __launch_bounds__(256, 4) void k_premix(const float* __restrict__ x,
                                                   const float* __restrict__ Wa,
                                                   const float* __restrict__ ba,
                                                   float* __restrict__ A,
                                                   float* __restrict__ Bm) {
    int tid = threadIdx.x;
    int q = tid >> 6;                       // quarter (wave-uniform)
    int p = blockIdx.x * 64 + (tid & 63);   // point over NB*NPTS
    float4 xv[8];
    {
        const float4* xr = (const float4*)(x + (size_t)p * 32);
        #pragma unroll
        for (int u = 0; u < 8; ++u) xv[u] = xr[u];
    }
    const float* W0 = Wa + q * 32 * 64;     // rows q*32..q*32+31
    float acc[32];
    #pragma unroll
    for (int o = 0; o < 32; ++o) acc[o] = 0.f;
    #pragma unroll 2
    for (int c4 = 0; c4 < 8; ++c4) {
        float4 v = xv[c4];
        #pragma unroll
        for (int o = 0; o < 32; ++o) {
            const float* w = W0 + o * 64 + c4 * 4;   // uniform -> s_load
            acc[o] += v.x * w[0] + v.y * w[1] + v.z * w[2] + v.w * w[3];
        }
    }
    {
        float4* op = (float4*)(A + (size_t)p * 128 + q * 32);
        #pragma unroll
        for (int o4 = 0; o4 < 8; ++o4)
            op[o4] = make_float4(acc[o4 * 4], acc[o4 * 4 + 1], acc[o4 * 4 + 2], acc[o4 * 4 + 3]);
    }
    #pragma unroll
    for (int o = 0; o < 32; ++o) acc[o] = ba[q * 32 + o];
    #pragma unroll 2
    for (int c4 = 0; c4 < 8; ++c4) {
        float4 v = xv[c4];
        #pragma unroll
        for (int o = 0; o < 32; ++o) {
            const float* w1 = W0 + o * 64 + c4 * 4;
            const float* w2 = w1 + 32;
            acc[o] += v.x * (w2[0] - w1[0]) + v.y * (w2[1] - w1[1]) +
                      v.z * (w2[2] - w1[2]) + v.w * (w2[3] - w1[3]);
        }
    }
    {
        float4* op = (float4*)(Bm + (size_t)p * 128 + q * 32);
        #pragma unroll
        for (int o4 = 0; o4 < 8; ++o4)
            op[o4] = make_float4(acc[o4 * 4], acc[o4 * 4 + 1], acc[o4 * 4 + 2], acc[o4 * 4 + 3]);
    }
}

// ---------------- kNN via MFMA Gram (bf16 3-way split, 6 terms), BARRIER-FREE ----------------
// Wave w computes AND selects rows [w*64,(w+1)*64): Dl tile is wave-private, so no
// __syncthreads needed — waves free-run, overlapping MFMA and selection phases.
// Selection reads batched x4; flush ballot once per 4 j's (trigger cnt >= C-3).
template <int K, int JS, int C>
__global__ __launch_bounds__(256, 2) void k_knn_mfma(const unsigned short* __restrict__ xh,
                                                     const unsigned short* __restrict__ xm,
                                                     const unsigned short* __restrict__ xl,
                                                     const float* __restrict__ sqg,
                                                     float* __restrict__ cand_d,
                                                     int* __restrict__ cand_i) {
    constexpr int JR = NPTS / JS;            // 1024
    constexpr int NCH = JR / 32;             // 32 chunks
    constexpr int BPB = (NPTS / 256) * JS;   // 256 blocks per batch
    constexpr int DS = 38;                   // Dl row stride (2-way max both sides)

    __shared__ float Dl[256 * DS];
    __shared__ float bufd[C * 256];          // transposed append buffer (conflict-free)
    __shared__ int   bufj[C * 256];

    int tid = threadIdx.x;
    int bid = blockIdx.x;
    int b = bid / BPB;
    int r0b = bid - b * BPB;
    int itile = r0b / JS;
    int jseg = r0b - itile * JS;

    const unsigned short* xhb = xh + ((size_t)b * NPTS) * 32;
    const unsigned short* xmb = xm + ((size_t)b * NPTS) * 32;
    const unsigned short* xlb = xl + ((size_t)b * NPTS) * 32;
    const float* sqb = sqg + (size_t)b * NPTS;

    int lane = tid & 63;
    int w = tid >> 6;          // wave 0..3 -> i rows [w*64, w*64+64)
    int g = lane >> 4;         // k-group: k = g*8 + e
    int r15 = lane & 15;

    // A fragments hoisted (constant over the whole j scan): 12 frags = 48 VGPR
    short8v ah[4], am[4], al[4];
    #pragma unroll
    for (int t = 0; t < 4; ++t) {
        size_t ii = (size_t)(itile * 256 + w * 64 + t * 16 + r15);
        ah[t] = *(const short8v*)(xhb + ii * 32 + g * 8);
        am[t] = *(const short8v*)(xmb + ii * 32 + g * 8);
        al[t] = *(const short8v*)(xlb + ii * 32 + g * 8);
    }

    float bd[K]; int bi[K];                  // sorted ascending, registers
    #pragma unroll
    for (int r = 0; r < K; ++r) { bd[r] = 1e30f; bi[r] = 0; }
    float thr = 1e30f;
    int cnt = 0;

    auto flush = [&]() {
        #pragma unroll
        for (int u = 0; u < C; ++u) {
            float dv = bufd[u * 256 + tid];
            int jv = bufj[u * 256 + tid];
            float dd = (u < cnt) ? dv : 1e30f;   // 1e30 never inserts (strict <)
            int ji = jv;
            #pragma unroll
            for (int r = 0; r < K; ++r) {
                bool c = dd < bd[r];
                float tf = bd[r]; int ti = bi[r];
                bd[r] = c ? dd : bd[r]; bi[r] = c ? ji : bi[r];
                dd = c ? tf : dd;       ji = c ? ti : ji;
            }
        }
        cnt = 0; thr = bd[K - 1];
    };

    int jbase = jseg * JR;
    #pragma unroll 1
    for (int ch = 0; ch < NCH; ++ch) {
        int j0 = jbase + ch * 32;
        // B fragments for this chunk (2 j-tiles of 16, 3 levels)
        short8v bh0, bm0, bl0, bh1, bm1, bl1;
        {
            size_t ja = (size_t)(j0 + r15);
            size_t jb = (size_t)(j0 + 16 + r15);
            bh0 = *(const short8v*)(xhb + ja * 32 + g * 8);
            bm0 = *(const short8v*)(xmb + ja * 32 + g * 8);
            bl0 = *(const short8v*)(xlb + ja * 32 + g * 8);
            bh1 = *(const short8v*)(xhb + jb * 32 + g * 8);
            bm1 = *(const short8v*)(xmb + jb * 32 + g * 8);
            bl1 = *(const short8v*)(xlb + jb * 32 + g * 8);
        }
        #pragma unroll
        for (int t = 0; t < 4; ++t) {
            {
                f32x4 acc = {0.f, 0.f, 0.f, 0.f};
                acc = __builtin_amdgcn_mfma_f32_16x16x32_bf16(am[t], bm0, acc, 0, 0, 0);
                acc = __builtin_amdgcn_mfma_f32_16x16x32_bf16(ah[t], bl0, acc, 0, 0, 0);
                acc = __builtin_amdgcn_mfma_f32_16x16x32_bf16(al[t], bh0, acc, 0, 0, 0);
                acc = __builtin_amdgcn_mfma_f32_16x16x32_bf16(ah[t], bm0, acc, 0, 0, 0);
                acc = __builtin_amdgcn_mfma_f32_16x16x32_bf16(am[t], bh0, acc, 0, 0, 0);
                acc = __builtin_amdgcn_mfma_f32_16x16x32_bf16(ah[t], bh0, acc, 0, 0, 0);
                int il = w * 64 + t * 16 + g * 4;
                Dl[(il + 0) * DS + r15] = acc[0];
                Dl[(il + 1) * DS + r15] = acc[1];
                Dl[(il + 2) * DS + r15] = acc[2];
                Dl[(il + 3) * DS + r15] = acc[3];
            }
            {
                f32x4 acc = {0.f, 0.f, 0.f, 0.f};
                acc = __builtin_amdgcn_mfma_f32_16x16x32_bf16(am[t], bm1, acc, 0, 0, 0);
                acc = __builtin_amdgcn_mfma_f32_16x16x32_bf16(ah[t], bl1, acc, 0, 0, 0);
                acc = __builtin_amdgcn_mfma_f32_16x16x32_bf16(al[t], bh1, acc, 0, 0, 0);
                acc = __builtin_amdgcn_mfma_f32_16x16x32_bf16(ah[t], bm1, acc, 0, 0, 0);
                acc = __builtin_amdgcn_mfma_f32_16x16x32_bf16(am[t], bh1, acc, 0, 0, 0);
                acc = __builtin_amdgcn_mfma_f32_16x16x32_bf16(ah[t], bh1, acc, 0, 0, 0);
                int il = w * 64 + t * 16 + g * 4;
                Dl[(il + 0) * DS + 16 + r15] = acc[0];
                Dl[(il + 1) * DS + 16 + r15] = acc[1];
                Dl[(il + 2) * DS + 16 + r15] = acc[2];
                Dl[(il + 3) * DS + 16 + r15] = acc[3];
            }
        }
        // selection (wave-private Dl rows; intra-wave lgkmcnt ordering suffices).
        // Batched x4: independent reads, then ordered appends (j ascending).
        #pragma unroll 1
        for (int jq = 0; jq < 32; jq += 4) {
            float v0 = Dl[tid * DS + jq + 0];
            float v1 = Dl[tid * DS + jq + 1];
            float v2 = Dl[tid * DS + jq + 2];
            float v3 = Dl[tid * DS + jq + 3];
            int j = j0 + jq;
            float d0 = sqb[j + 0] - 2.f * v0;   // rank key (sq_i const offset per i)
            float d1 = sqb[j + 1] - 2.f * v1;
            float d2 = sqb[j + 2] - 2.f * v2;
            float d3 = sqb[j + 3] - 2.f * v3;
            // strict < : on distance tie the earlier (lower-index) j stays -> jax tie-break
            if (d0 < thr) { bufd[cnt * 256 + tid] = d0; bufj[cnt * 256 + tid] = j + 0; cnt++; }
            if (d1 < thr) { bufd[cnt * 256 + tid] = d1; bufj[cnt * 256 + tid] = j + 1; cnt++; }
            if (d2 < thr) { bufd[cnt * 256 + tid] = d2; bufj[cnt * 256 + tid] = j + 2; cnt++; }
            if (d3 < thr) { bufd[cnt * 256 + tid] = d3; bufj[cnt * 256 + tid] = j + 3; cnt++; }
            if (__any(cnt >= C - 3)) flush();   // capacity: cnt <= C-4 at group top
        }
    }
    flush();
    size_t base = ((size_t)jseg * (NB * NPTS) + (size_t)(b * NPTS) + itile * 256 + tid) * K;
    #pragma unroll
    for (int r = 0; r < K; ++r) { cand_d[base + r] = bd[r]; cand_i[base + r] = bi[r]; }
}

// ---------------- merge JS candidate lists -> final idx [B*N, K] ----------------
template <int K, int JS>
__global__ void k_knn_merge(const float* __restrict__ cand_d, const int* __restrict__ cand_i,
                            int* __restrict__ idx_out) {
    constexpr int M = JS * K;
    __shared__ float md[64 * (M + 1)];
    __shared__ int   mi[64 * (M + 1)];
    int tid = threadIdx.x;                  // 64 threads
    int pbase = blockIdx.x * 64;
    for (int v = tid; v < 64 * M; v += 64) {
        int s = v / (64 * K);
        int rem = v - s * 64 * K;
        int p = rem / K;
        size_t g = ((size_t)s * (NB * NPTS) + pbase + p) * K + (rem - p * K);
        md[p * (M + 1) + s * K + (rem - p * K)] = cand_d[g];
        mi[p * (M + 1) + s * K + (rem - p * K)] = cand_i[g];
    }
    __syncthreads();
    float* rd = md + tid * (M + 1);
    int* ri = mi + tid * (M + 1);
    int* op = idx_out + (size_t)(pbase + tid) * K;
    for (int r = 0; r < K; ++r) {
        float best = 1e30f; int bj = 0x7fffffff; int bs = 0;
        for (int u = 0; u < M; ++u) {
            float dv = rd[u]; int jv = ri[u];
            if (dv < best || (dv == best && jv < bj)) { best = dv; bj = jv; bs = u; }
        }
        rd[bs] = 1e30f;
        op[r] = bj;
    }
}

// ---------------- EdgeConv v4: register-lean 6x8 / 4x8 output tiles ----------------
template <int K>
__global__ __launch_bounds__(256, 1)
void k_edgeconv4(const int* __restrict__ idx,
                 const float* __restrict__ A, const float* __restrict__ Bm,
                 const float* __restrict__ WbTg, const float* __restrict__ bb,
                 float* __restrict__ y) {
    constexpr int TE = (K == 12) ? 6 : 4;     // edges per thread
    constexpr int EPI = 16 * TE;              // edges per iter: 96 / 64
    constexpr int PI = EPI / K;               // points per iter: 8 / 16
    constexpr int ITERS = 64 / PI;            // 8 / 4
    constexpr int NT = 256;
    constexpr int HS = 132;                   // H1 row stride

    __shared__ __align__(16) float WbT[128 * 128];
    __shared__ __align__(16) float bb_s[128];
    __shared__ __align__(16) float H1[EPI * HS];
    __shared__ __align__(16) float Pm[(K == 12) ? 16 * 128 : 4];

    int tid = threadIdx.x;
    {
        const float4* sb = (const float4*)WbTg;
        float4* db = (float4*)WbT;
        #pragma unroll
        for (int i = 0; i < 16; ++i) db[tid + i * NT] = sb[tid + i * NT];
        if (tid < 128) bb_s[tid] = bb[tid];
    }

    int b = blockIdx.x >> 7;
    int pbase = (blockIdx.x & 127) * 64;
    const int* idxb = idx + ((size_t)b * NPTS) * K;
    const float4* A4 = (const float4*)(A + ((size_t)b * NPTS) * 128);
    const float4* B4 = (const float4*)(Bm + ((size_t)b * NPTS) * 128);
    float* yb = y + ((size_t)b * NPTS) * 128;

    int og = tid & 15;        // 16 out-groups x 8 outputs
    int eg = tid >> 4;        // 16 edge-groups x TE edges
    int ebase = eg * TE;

    for (int it = 0; it < ITERS; ++it) {
        int pt0 = pbase + it * PI;
        #pragma unroll
        for (int r = 0; r < (EPI * 32) / NT; ++r) {
            int u = tid + r * NT;
            int e = u >> 5, c4 = u & 31;
            int p = pt0 + e / K;
            int j = idxb[(size_t)p * K + (e % K)];
            float4 av = A4[(size_t)j * 32 + c4];
            float4 bv = B4[(size_t)p * 32 + c4];
            *(float4*)&H1[e * HS + 4 * c4] = lrelu4(add4(av, bv));
        }
        __syncthreads();
        float4 acc[TE][2];
        {
            float4 blo = *(const float4*)&bb_s[og * 8];
            float4 bhi = *(const float4*)&bb_s[og * 8 + 4];
            #pragma unroll
            for (int e = 0; e < TE; ++e) { acc[e][0] = blo; acc[e][1] = bhi; }
        }
        #pragma unroll 2
        for (int c4 = 0; c4 < 32; ++c4) {
            float4 hv[TE];
            #pragma unroll
            for (int e = 0; e < TE; ++e)
                hv[e] = *(const float4*)&H1[(ebase + e) * HS + 4 * c4];
            #pragma unroll
            for (int j = 0; j < 4; ++j) {
                const float* wr = &WbT[(4 * c4 + j) * 128 + og * 8];
                float4 wlo = *(const float4*)wr;
                float4 whi = *(const float4*)(wr + 4);
                #pragma unroll
                for (int e = 0; e < TE; ++e) {
                    float hc = (j == 0) ? hv[e].x : (j == 1) ? hv[e].y : (j == 2) ? hv[e].z : hv[e].w;
                    acc[e][0].x += hc * wlo.x; acc[e][0].y += hc * wlo.y;
                    acc[e][0].z += hc * wlo.z; acc[e][0].w += hc * wlo.w;
                    acc[e][1].x += hc * whi.x; acc[e][1].y += hc * whi.y;
                    acc[e][1].z += hc * whi.z; acc[e][1].w += hc * whi.w;
                }
            }
        }
        float4 mlo = lrelu4(acc[0][0]), mhi = lrelu4(acc[0][1]);
        #pragma unroll
        for (int e = 1; e < TE; ++e) {
            mlo = fmax4(mlo, lrelu4(acc[e][0]));
            mhi = fmax4(mhi, lrelu4(acc[e][1]));
        }
        if constexpr (K == 4) {
            float4* yp = (float4*)&yb[((size_t)(pt0 + eg)) * 128 + og * 8];
            yp[0] = mlo; yp[1] = mhi;
            __syncthreads();
        } else {
            *(float4*)&Pm[eg * 128 + og * 8] = mlo;
            *(float4*)&Pm[eg * 128 + og * 8 + 4] = mhi;
            __syncthreads();
            #pragma unroll
            for (int r = 0; r < 4; ++r) {
                int u = tid + r * NT;
                int p = u >> 7, o = u & 127;
                yb[((size_t)(pt0 + p)) * 128 + o] =
                    fmaxf(Pm[(2 * p) * 128 + o], Pm[(2 * p + 1) * 128 + o]);
            }
        }
    }
}

// ---------------- conv_mid: y -> x1 fp32 + sq1 + bf16 h/m/l split ----------------
__global__ void k_conv_mid(const float* __restrict__ xin, const float* __restrict__ W,
                           const float* __restrict__ bias, float* __restrict__ out,
                           float* __restrict__ sq, unsigned short* __restrict__ xh,
                           unsigned short* __restrict__ xm, unsigned short* __restrict__ xl) {
    int gid = blockIdx.x * blockDim.x + threadIdx.x;
    const float4* row = (const float4*)(xin + (size_t)gid * 128);
    float acc[32];
    #pragma unroll
    for (int o = 0; o < 32; ++o) acc[o] = bias[o];
    #pragma unroll 2
    for (int c4 = 0; c4 < 32; ++c4) {
        float4 v = row[c4];
        #pragma unroll
        for (int o = 0; o < 32; ++o) {
            const float* w = W + o * 128 + c4 * 4;   // uniform -> s_load
            acc[o] += v.x * w[0] + v.y * w[1] + v.z * w[2] + v.w * w[3];
        }
    }
    float s = 0.f;
    float4* op = (float4*)(out + (size_t)gid * 32);
    unsigned int* hrow = (unsigned int*)(xh + (size_t)gid * 32);
    unsigned int* mrow = (unsigned int*)(xm + (size_t)gid * 32);
    unsigned int* lrow = (unsigned int*)(xl + (size_t)gid * 32);
    #pragma unroll
    for (int o4 = 0; o4 < 8; ++o4) {
        float4 v = make_float4(lrelu(acc[o4 * 4]), lrelu(acc[o4 * 4 + 1]),
                               lrelu(acc[o4 * 4 + 2]), lrelu(acc[o4 * 4 + 3]));
        s += v.x * v.x + v.y * v.y + v.z * v.z + v.w * v.w;
        op[o4] = v;
        unsigned int hp[2], mp[2], lp[2];
        split3(v, hp, mp, lp);
        *(uint2*)(hrow + o4 * 2) = make_uint2(hp[0], hp[1]);
        *(uint2*)(mrow + o4 * 2) = make_uint2(mp[0], mp[1]);
        *(uint2*)(lrow + o4 * 2) = make_uint2(lp[0], lp[1]);
    }
    sq[gid] = s;
}

// ---------------- decoder: y1 [B*N,128] -> out [B*N,12] ----------------
__global__ void k_decoder(const float* __restrict__ xin,
                          const float* __restrict__ W0, const float* __restrict__ b0,
                          const float* __restrict__ W1, const float* __restrict__ b1,
                          const float* __restrict__ W2, const float* __restrict__ b2,
                          float* __restrict__ out) {
    int gid = blockIdx.x * blockDim.x + threadIdx.x;
    const float4* row = (const float4*)(xin + (size_t)gid * 128);
    float h0[6];
    #pragma unroll
    for (int o = 0; o < 6; ++o) h0[o] = b0[o];
    #pragma unroll 4
    for (int c4 = 0; c4 < 32; ++c4) {
        float4 v = row[c4];
        #pragma unroll
        for (int o = 0; o < 6; ++o) {
            const float* w = W0 + o * 128 + c4 * 4;
            h0[o] += v.x * w[0] + v.y * w[1] + v.z * w[2] + v.w * w[3];
        }
    }
    #pragma unroll
    for (int o = 0; o < 6; ++o) h0[o] = lrelu(h0[o]);
    float h1[12];
    #pragma unroll
    for (int o = 0; o < 12; ++o) {
        float a = b1[o];
        #pragma unroll
        for (int j = 0; j < 6; ++j) a += W1[o * 6 + j] * h0[j];
        h1[o] = lrelu(a);
    }
    float* op = out + (size_t)gid * 12;
    #pragma unroll
    for (int o = 0; o < 12; ++o) {
        float a = b2[o];
        #pragma unroll
        for (int j = 0; j < 12; ++j) a += W2[o * 12 + j] * h1[j];
        op[o] = a;
    }
}

extern "C" void kernel_launch(void* const* d_in, const int* in_sizes, int n_in,
                              void* d_out, int out_size, void* d_ws, size_t ws_size,
                              hipStream_t stream) {
    const float* feature = (const float*)d_in[0];
    const float* Wc0 = (const float*)d_in[1];
    const float* bc0 = (const float*)d_in[2];
    const float* We0a = (const float*)d_in[3];
    const float* be0a = (const float*)d_in[4];
    const float* We0b = (const float*)d_in[5];
    const float* be0b = (const float*)d_in[6];
    const float* Wc1 = (const float*)d_in[7];
    const float* bc1 = (const float*)d_in[8];
    const float* We1a = (const float*)d_in[9];
    const float* be1a = (const float*)d_in[10];
    const float* We1b = (const float*)d_in[11];
    const float* be1b = (const float*)d_in[12];
    const float* Wd0 = (const float*)d_in[13];
    const float* bd0 = (const float*)d_in[14];
    const float* Wd1 = (const float*)d_in[15];
    const float* bd1 = (const float*)d_in[16];
    const float* Wd2 = (const float*)d_in[17];
    const float* bd2 = (const float*)d_in[18];
    float* out = (float*)d_out;

    float* f = (float*)d_ws;
    // layout (floats), total ~30.7 MB with phase-based aliasing
    float* x0   = f;                       // [0, 524288)
    float* x1   = f + 524288;              // [524288, 1048576)
    int*   idx0 = (int*)(f + 1048576);     // 196608
    int*   idx1 = (int*)(f + 1245184);     // 65536
    float* wT   = f + 1310720;             // 32768 (WbT0 | WbT1)
    float* Zab  = f + 1343488;             // 4194304: A | Bm
    float* Abuf = Zab;                     // 2097152
    float* Bbuf = Zab + 2097152;           // 2097152
    float* Y    = f + 5537792;             // 2097152: y0, later y1
    float* sq0  = f + 7634944;             // 16384
    float* sq1  = f + 7651328;             // 16384 (end 7667712 ~ 30.7 MB)
    // cand0 aliases Zab (dead until premix): 8*16384*12 = 1572864 floats each
    float* c0d  = Zab;
    int*   c0i  = (int*)(Zab + 1572864);   // ends 3145728 < 4194304
    // xh0/xm0/xl0 alias Y (y0 written later by edgeconv): 262144 floats each
    unsigned short* xh0 = (unsigned short*)Y;
    unsigned short* xm0 = (unsigned short*)(Y + 262144);
    unsigned short* xl0 = (unsigned short*)(Y + 524288);
    // xh1/xm1/xl1 alias Zab (c0 dead after merge; premix1 writes A/B after knn<4>)
    unsigned short* xh1 = (unsigned short*)Zab;
    unsigned short* xm1 = (unsigned short*)(Zab + 262144);
    unsigned short* xl1 = (unsigned short*)(Zab + 524288);
    // cand1 aliases Y (y0 and splits dead by then): 524288 floats each
    float* c1d  = Y;
    int*   c1i  = (int*)(Y + 524288);      // ends 1048576 < 2097152
    float* WbT0 = wT;
    float* WbT1 = wT + 16384;

    k_transpose_w<<<128, 256, 0, stream>>>(We0b, We1b, wT);
    k_conv_in<<<64, 256, 0, stream>>>(feature, Wc0, bc0, x0, sq0, xh0, xm0, xl0);
    k_knn_mfma<12, 8, 12><<<512, 256, 0, stream>>>(xh0, xm0, xl0, sq0, c0d, c0i);
    k_knn_merge<12, 8><<<256, 64, 0, stream>>>(c0d, c0i, idx0);
    k_premix<<<256, 256, 0, stream>>>(x0, We0a, be0a, Abuf, Bbuf);
    k_edgeconv4<12><<<256, 256, 0, stream>>>(idx0, Abuf, Bbuf, WbT0, be0b, Y);
    k_conv_mid<<<64, 256, 0, stream>>>(Y, Wc1, bc1, x1, sq1, xh1, xm1, xl1);
    k_knn_mfma<4, 8, 8><<<512, 256, 0, stream>>>(xh1, xm1, xl1, sq1, c1d, c1i);
    k_knn_merge<4, 8><<<256, 64, 0, stream>>>(c1d, c1i, idx1);
    k_premix<<<256, 256, 0, stream>>>(x1, We1a, be1a, Abuf, Bbuf);
    k_edgeconv4<4><<<256, 256, 0, stream>>>(idx1, Abuf, Bbuf, WbT1, be1b, Y);
    k_decoder<<<64, 256, 0, stream>>>(Y, Wd0, bd0, Wd1, bd1, Wd2, bd2, out);
}

// Round 19
// 709.655 us; speedup vs baseline: 1.6673x; 1.2239x over previous
//
#include <hip/hip_runtime.h>

#define NPTS 8192
#define NB 2

typedef __attribute__((ext_vector_type(8))) short short8v;   // 8 bf16 (4 VGPRs)
typedef __attribute__((ext_vector_type(4))) float f32x4;

__device__ __forceinline__ float lrelu(float x) { return x > 0.f ? x : 0.2f * x; }
__device__ __forceinline__ float4 lrelu4(float4 a) {
    return make_float4(lrelu(a.x), lrelu(a.y), lrelu(a.z), lrelu(a.w));
}
__device__ __forceinline__ float4 fmax4(float4 a, float4 b) {
    return make_float4(fmaxf(a.x, b.x), fmaxf(a.y, b.y), fmaxf(a.z, b.z), fmaxf(a.w, b.w));
}
__device__ __forceinline__ float4 add4(float4 a, float4 b) {
    return make_float4(a.x + b.x, a.y + b.y, a.z + b.z, a.w + b.w);
}
__device__ __forceinline__ unsigned short f2bf(float f) {     // RNE bf16
    unsigned int u = __float_as_uint(f);
    return (unsigned short)((u + 0x7FFFu + ((u >> 16) & 1u)) >> 16);
}
__device__ __forceinline__ float bf2f(unsigned short h) {
    return __uint_as_float(((unsigned int)h) << 16);
}

// ---------------- prep: transpose layer-2 weights into ws (WbT[c][o]) ----------------
__global__ void k_transpose_w(const float* __restrict__ Wb0, const float* __restrict__ Wb1,
                              float* __restrict__ out) {
    int t = blockIdx.x * 256 + threadIdx.x;
    if (t < 16384)      out[t] = Wb0[(t & 127) * 128 + (t >> 7)];
    else if (t < 32768) { int i = t - 16384; out[t] = Wb1[(i & 127) * 128 + (i >> 7)]; }
}

// 3-way bf16 split of a float4, packed into 2 uints per level
__device__ __forceinline__ void split3(float4 v, unsigned int* hp, unsigned int* mp,
                                       unsigned int* lp) {
    float c[4] = {v.x, v.y, v.z, v.w};
    unsigned short h[4], m[4], l[4];
    #pragma unroll
    for (int i = 0; i < 4; ++i) {
        h[i] = f2bf(c[i]);
        float r1 = c[i] - bf2f(h[i]);
        m[i] = f2bf(r1);
        float r2 = r1 - bf2f(m[i]);
        l[i] = f2bf(r2);
    }
    hp[0] = (unsigned int)h[0] | ((unsigned int)h[1] << 16);
    hp[1] = (unsigned int)h[2] | ((unsigned int)h[3] << 16);
    mp[0] = (unsigned int)m[0] | ((unsigned int)m[1] << 16);
    mp[1] = (unsigned int)m[2] | ((unsigned int)m[3] << 16);
    lp[0] = (unsigned int)l[0] | ((unsigned int)l[1] << 16);
    lp[1] = (unsigned int)l[2] | ((unsigned int)l[3] << 16);
}

// ---------------- conv_in: feature -> x0 fp32 + sq0 + bf16 h/m/l split ----------------
__global__ void k_conv_in(const float* __restrict__ f, const float* __restrict__ W,
                          const float* __restrict__ bias, float* __restrict__ out,
                          float* __restrict__ sq, unsigned short* __restrict__ xh,
                          unsigned short* __restrict__ xm, unsigned short* __restrict__ xl) {
    int gid = blockIdx.x * blockDim.x + threadIdx.x;   // over B*N
    int b = gid >> 13, n = gid & (NPTS - 1);
    const float* fb = f + ((size_t)b << 20) + n;       // b*128*8192
    float acc[32];
    #pragma unroll
    for (int o = 0; o < 32; ++o) acc[o] = bias[o];
    #pragma unroll 4
    for (int c = 0; c < 128; ++c) {
        float xc = fb[(size_t)c * NPTS];               // coalesced across lanes
        #pragma unroll
        for (int o = 0; o < 32; ++o) acc[o] += xc * W[o * 128 + c];  // uniform -> s_load
    }
    float s = 0.f;
    float4* op = (float4*)(out + (size_t)gid * 32);
    unsigned int* hrow = (unsigned int*)(xh + (size_t)gid * 32);
    unsigned int* mrow = (unsigned int*)(xm + (size_t)gid * 32);
    unsigned int* lrow = (unsigned int*)(xl + (size_t)gid * 32);
    #pragma unroll
    for (int o4 = 0; o4 < 8; ++o4) {
        float4 v = make_float4(lrelu(acc[o4 * 4]), lrelu(acc[o4 * 4 + 1]),
                               lrelu(acc[o4 * 4 + 2]), lrelu(acc[o4 * 4 + 3]));
        s += v.x * v.x + v.y * v.y + v.z * v.z + v.w * v.w;
        op[o4] = v;
        unsigned int hp[2], mp[2], lp[2];
        split3(v, hp, mp, lp);
        *(uint2*)(hrow + o4 * 2) = make_uint2(hp[0], hp[1]);
        *(uint2*)(mrow + o4 * 2) = make_uint2(mp[0], mp[1]);
        *(uint2*)(lrow + o4 * 2) = make_uint2(lp[0], lp[1]);
    }
    sq[gid] = s;
}

// ---------------- premix: A = x @ Wa1^T ; Bm = x @ (Wa2-Wa1)^T + ba ----------------
// (256,2): 128-VGPR budget so xv[8]+acc[32] stay in registers (R18 fix: (256,4)
// capped at 64 VGPR -> acc spilled to scratch -> 384 MB of L2/HBM traffic).
__global__ __launch_bounds__(256, 2) void k_premix(const float* __restrict__ x,
                                                   const float* __restrict__ Wa,
                                                   const float* __restrict__ ba,
                                                   float* __restrict__ A,
                                                   float* __restrict__ Bm) {
    int tid = threadIdx.x;
    int q = tid >> 6;                       // quarter (wave-uniform)
    int p = blockIdx.x * 64 + (tid & 63);   // point over NB*NPTS
    float4 xv[8];
    {
        const float4* xr = (const float4*)(x + (size_t)p * 32);
        #pragma unroll
        for (int u = 0; u < 8; ++u) xv[u] = xr[u];
    }
    const float* W0 = Wa + q * 32 * 64;     // rows q*32..q*32+31
    float acc[32];
    #pragma unroll
    for (int o = 0; o < 32; ++o) acc[o] = 0.f;
    #pragma unroll 2
    for (int c4 = 0; c4 < 8; ++c4) {
        float4 v = xv[c4];
        #pragma unroll
        for (int o = 0; o < 32; ++o) {
            const float* w = W0 + o * 64 + c4 * 4;   // uniform -> s_load
            acc[o] += v.x * w[0] + v.y * w[1] + v.z * w[2] + v.w * w[3];
        }
    }
    {
        float4* op = (float4*)(A + (size_t)p * 128 + q * 32);
        #pragma unroll
        for (int o4 = 0; o4 < 8; ++o4)
            op[o4] = make_float4(acc[o4 * 4], acc[o4 * 4 + 1], acc[o4 * 4 + 2], acc[o4 * 4 + 3]);
    }
    #pragma unroll
    for (int o = 0; o < 32; ++o) acc[o] = ba[q * 32 + o];
    #pragma unroll 2
    for (int c4 = 0; c4 < 8; ++c4) {
        float4 v = xv[c4];
        #pragma unroll
        for (int o = 0; o < 32; ++o) {
            const float* w1 = W0 + o * 64 + c4 * 4;
            const float* w2 = w1 + 32;
            acc[o] += v.x * (w2[0] - w1[0]) + v.y * (w2[1] - w1[1]) +
                      v.z * (w2[2] - w1[2]) + v.w * (w2[3] - w1[3]);
        }
    }
    {
        float4* op = (float4*)(Bm + (size_t)p * 128 + q * 32);
        #pragma unroll
        for (int o4 = 0; o4 < 8; ++o4)
            op[o4] = make_float4(acc[o4 * 4], acc[o4 * 4 + 1], acc[o4 * 4 + 2], acc[o4 * 4 + 3]);
    }
}

// ---------------- kNN via MFMA Gram (bf16 3-way split, 6 terms), BARRIER-FREE ----------------
// Wave w computes AND selects rows [w*64,(w+1)*64): Dl tile is wave-private, so no
// __syncthreads needed — waves free-run, overlapping MFMA and selection phases.
// Selection reads batched x4; flush ballot once per 4 j's (trigger cnt >= C-3).
template <int K, int JS, int C>
__global__ __launch_bounds__(256, 2) void k_knn_mfma(const unsigned short* __restrict__ xh,
                                                     const unsigned short* __restrict__ xm,
                                                     const unsigned short* __restrict__ xl,
                                                     const float* __restrict__ sqg,
                                                     float* __restrict__ cand_d,
                                                     int* __restrict__ cand_i) {
    constexpr int JR = NPTS / JS;            // 1024
    constexpr int NCH = JR / 32;             // 32 chunks
    constexpr int BPB = (NPTS / 256) * JS;   // 256 blocks per batch
    constexpr int DS = 38;                   // Dl row stride (2-way max both sides)

    __shared__ float Dl[256 * DS];
    __shared__ float bufd[C * 256];          // transposed append buffer (conflict-free)
    __shared__ int   bufj[C * 256];

    int tid = threadIdx.x;
    int bid = blockIdx.x;
    int b = bid / BPB;
    int r0b = bid - b * BPB;
    int itile = r0b / JS;
    int jseg = r0b - itile * JS;

    const unsigned short* xhb = xh + ((size_t)b * NPTS) * 32;
    const unsigned short* xmb = xm + ((size_t)b * NPTS) * 32;
    const unsigned short* xlb = xl + ((size_t)b * NPTS) * 32;
    const float* sqb = sqg + (size_t)b * NPTS;

    int lane = tid & 63;
    int w = tid >> 6;          // wave 0..3 -> i rows [w*64, w*64+64)
    int g = lane >> 4;         // k-group: k = g*8 + e
    int r15 = lane & 15;

    // A fragments hoisted (constant over the whole j scan): 12 frags = 48 VGPR
    short8v ah[4], am[4], al[4];
    #pragma unroll
    for (int t = 0; t < 4; ++t) {
        size_t ii = (size_t)(itile * 256 + w * 64 + t * 16 + r15);
        ah[t] = *(const short8v*)(xhb + ii * 32 + g * 8);
        am[t] = *(const short8v*)(xmb + ii * 32 + g * 8);
        al[t] = *(const short8v*)(xlb + ii * 32 + g * 8);
    }

    float bd[K]; int bi[K];                  // sorted ascending, registers
    #pragma unroll
    for (int r = 0; r < K; ++r) { bd[r] = 1e30f; bi[r] = 0; }
    float thr = 1e30f;
    int cnt = 0;

    auto flush = [&]() {
        #pragma unroll
        for (int u = 0; u < C; ++u) {
            float dv = bufd[u * 256 + tid];
            int jv = bufj[u * 256 + tid];
            float dd = (u < cnt) ? dv : 1e30f;   // 1e30 never inserts (strict <)
            int ji = jv;
            #pragma unroll
            for (int r = 0; r < K; ++r) {
                bool c = dd < bd[r];
                float tf = bd[r]; int ti = bi[r];
                bd[r] = c ? dd : bd[r]; bi[r] = c ? ji : bi[r];
                dd = c ? tf : dd;       ji = c ? ti : ji;
            }
        }
        cnt = 0; thr = bd[K - 1];
    };

    int jbase = jseg * JR;
    #pragma unroll 1
    for (int ch = 0; ch < NCH; ++ch) {
        int j0 = jbase + ch * 32;
        // B fragments for this chunk (2 j-tiles of 16, 3 levels)
        short8v bh0, bm0, bl0, bh1, bm1, bl1;
        {
            size_t ja = (size_t)(j0 + r15);
            size_t jb = (size_t)(j0 + 16 + r15);
            bh0 = *(const short8v*)(xhb + ja * 32 + g * 8);
            bm0 = *(const short8v*)(xmb + ja * 32 + g * 8);
            bl0 = *(const short8v*)(xlb + ja * 32 + g * 8);
            bh1 = *(const short8v*)(xhb + jb * 32 + g * 8);
            bm1 = *(const short8v*)(xmb + jb * 32 + g * 8);
            bl1 = *(const short8v*)(xlb + jb * 32 + g * 8);
        }
        #pragma unroll
        for (int t = 0; t < 4; ++t) {
            {
                f32x4 acc = {0.f, 0.f, 0.f, 0.f};
                acc = __builtin_amdgcn_mfma_f32_16x16x32_bf16(am[t], bm0, acc, 0, 0, 0);
                acc = __builtin_amdgcn_mfma_f32_16x16x32_bf16(ah[t], bl0, acc, 0, 0, 0);
                acc = __builtin_amdgcn_mfma_f32_16x16x32_bf16(al[t], bh0, acc, 0, 0, 0);
                acc = __builtin_amdgcn_mfma_f32_16x16x32_bf16(ah[t], bm0, acc, 0, 0, 0);
                acc = __builtin_amdgcn_mfma_f32_16x16x32_bf16(am[t], bh0, acc, 0, 0, 0);
                acc = __builtin_amdgcn_mfma_f32_16x16x32_bf16(ah[t], bh0, acc, 0, 0, 0);
                int il = w * 64 + t * 16 + g * 4;
                Dl[(il + 0) * DS + r15] = acc[0];
                Dl[(il + 1) * DS + r15] = acc[1];
                Dl[(il + 2) * DS + r15] = acc[2];
                Dl[(il + 3) * DS + r15] = acc[3];
            }
            {
                f32x4 acc = {0.f, 0.f, 0.f, 0.f};
                acc = __builtin_amdgcn_mfma_f32_16x16x32_bf16(am[t], bm1, acc, 0, 0, 0);
                acc = __builtin_amdgcn_mfma_f32_16x16x32_bf16(ah[t], bl1, acc, 0, 0, 0);
                acc = __builtin_amdgcn_mfma_f32_16x16x32_bf16(al[t], bh1, acc, 0, 0, 0);
                acc = __builtin_amdgcn_mfma_f32_16x16x32_bf16(ah[t], bm1, acc, 0, 0, 0);
                acc = __builtin_amdgcn_mfma_f32_16x16x32_bf16(am[t], bh1, acc, 0, 0, 0);
                acc = __builtin_amdgcn_mfma_f32_16x16x32_bf16(ah[t], bh1, acc, 0, 0, 0);
                int il = w * 64 + t * 16 + g * 4;
                Dl[(il + 0) * DS + 16 + r15] = acc[0];
                Dl[(il + 1) * DS + 16 + r15] = acc[1];
                Dl[(il + 2) * DS + 16 + r15] = acc[2];
                Dl[(il + 3) * DS + 16 + r15] = acc[3];
            }
        }
        // selection (wave-private Dl rows; intra-wave lgkmcnt ordering suffices).
        // Batched x4: independent reads, then ordered appends (j ascending).
        #pragma unroll 1
        for (int jq = 0; jq < 32; jq += 4) {
            float v0 = Dl[tid * DS + jq + 0];
            float v1 = Dl[tid * DS + jq + 1];
            float v2 = Dl[tid * DS + jq + 2];
            float v3 = Dl[tid * DS + jq + 3];
            int j = j0 + jq;
            float d0 = sqb[j + 0] - 2.f * v0;   // rank key (sq_i const offset per i)
            float d1 = sqb[j + 1] - 2.f * v1;
            float d2 = sqb[j + 2] - 2.f * v2;
            float d3 = sqb[j + 3] - 2.f * v3;
            // strict < : on distance tie the earlier (lower-index) j stays -> jax tie-break
            if (d0 < thr) { bufd[cnt * 256 + tid] = d0; bufj[cnt * 256 + tid] = j + 0; cnt++; }
            if (d1 < thr) { bufd[cnt * 256 + tid] = d1; bufj[cnt * 256 + tid] = j + 1; cnt++; }
            if (d2 < thr) { bufd[cnt * 256 + tid] = d2; bufj[cnt * 256 + tid] = j + 2; cnt++; }
            if (d3 < thr) { bufd[cnt * 256 + tid] = d3; bufj[cnt * 256 + tid] = j + 3; cnt++; }
            if (__any(cnt >= C - 3)) flush();   // capacity: cnt <= C-4 at group top
        }
    }
    flush();
    size_t base = ((size_t)jseg * (NB * NPTS) + (size_t)(b * NPTS) + itile * 256 + tid) * K;
    #pragma unroll
    for (int r = 0; r < K; ++r) { cand_d[base + r] = bd[r]; cand_i[base + r] = bi[r]; }
}

// ---------------- merge JS candidate lists -> final idx [B*N, K] ----------------
template <int K, int JS>
__global__ void k_knn_merge(const float* __restrict__ cand_d, const int* __restrict__ cand_i,
                            int* __restrict__ idx_out) {
    constexpr int M = JS * K;
    __shared__ float md[64 * (M + 1)];
    __shared__ int   mi[64 * (M + 1)];
    int tid = threadIdx.x;                  // 64 threads
    int pbase = blockIdx.x * 64;
    for (int v = tid; v < 64 * M; v += 64) {
        int s = v / (64 * K);
        int rem = v - s * 64 * K;
        int p = rem / K;
        size_t g = ((size_t)s * (NB * NPTS) + pbase + p) * K + (rem - p * K);
        md[p * (M + 1) + s * K + (rem - p * K)] = cand_d[g];
        mi[p * (M + 1) + s * K + (rem - p * K)] = cand_i[g];
    }
    __syncthreads();
    float* rd = md + tid * (M + 1);
    int* ri = mi + tid * (M + 1);
    int* op = idx_out + (size_t)(pbase + tid) * K;
    for (int r = 0; r < K; ++r) {
        float best = 1e30f; int bj = 0x7fffffff; int bs = 0;
        for (int u = 0; u < M; ++u) {
            float dv = rd[u]; int jv = ri[u];
            if (dv < best || (dv == best && jv < bj)) { best = dv; bj = jv; bs = u; }
        }
        rd[bs] = 1e30f;
        op[r] = bj;
    }
}

// ---------------- EdgeConv v4: register-lean 6x8 / 4x8 output tiles ----------------
template <int K>
__global__ __launch_bounds__(256, 1)
void k_edgeconv4(const int* __restrict__ idx,
                 const float* __restrict__ A, const float* __restrict__ Bm,
                 const float* __restrict__ WbTg, const float* __restrict__ bb,
                 float* __restrict__ y) {
    constexpr int TE = (K == 12) ? 6 : 4;     // edges per thread
    constexpr int EPI = 16 * TE;              // edges per iter: 96 / 64
    constexpr int PI = EPI / K;               // points per iter: 8 / 16
    constexpr int ITERS = 64 / PI;            // 8 / 4
    constexpr int NT = 256;
    constexpr int HS = 132;                   // H1 row stride

    __shared__ __align__(16) float WbT[128 * 128];
    __shared__ __align__(16) float bb_s[128];
    __shared__ __align__(16) float H1[EPI * HS];
    __shared__ __align__(16) float Pm[(K == 12) ? 16 * 128 : 4];

    int tid = threadIdx.x;
    {
        const float4* sb = (const float4*)WbTg;
        float4* db = (float4*)WbT;
        #pragma unroll
        for (int i = 0; i < 16; ++i) db[tid + i * NT] = sb[tid + i * NT];
        if (tid < 128) bb_s[tid] = bb[tid];
    }

    int b = blockIdx.x >> 7;
    int pbase = (blockIdx.x & 127) * 64;
    const int* idxb = idx + ((size_t)b * NPTS) * K;
    const float4* A4 = (const float4*)(A + ((size_t)b * NPTS) * 128);
    const float4* B4 = (const float4*)(Bm + ((size_t)b * NPTS) * 128);
    float* yb = y + ((size_t)b * NPTS) * 128;

    int og = tid & 15;        // 16 out-groups x 8 outputs
    int eg = tid >> 4;        // 16 edge-groups x TE edges
    int ebase = eg * TE;

    for (int it = 0; it < ITERS; ++it) {
        int pt0 = pbase + it * PI;
        #pragma unroll
        for (int r = 0; r < (EPI * 32) / NT; ++r) {
            int u = tid + r * NT;
            int e = u >> 5, c4 = u & 31;
            int p = pt0 + e / K;
            int j = idxb[(size_t)p * K + (e % K)];
            float4 av = A4[(size_t)j * 32 + c4];
            float4 bv = B4[(size_t)p * 32 + c4];
            *(float4*)&H1[e * HS + 4 * c4] = lrelu4(add4(av, bv));
        }
        __syncthreads();
        float4 acc[TE][2];
        {
            float4 blo = *(const float4*)&bb_s[og * 8];
            float4 bhi = *(const float4*)&bb_s[og * 8 + 4];
            #pragma unroll
            for (int e = 0; e < TE; ++e) { acc[e][0] = blo; acc[e][1] = bhi; }
        }
        #pragma unroll 2
        for (int c4 = 0; c4 < 32; ++c4) {
            float4 hv[TE];
            #pragma unroll
            for (int e = 0; e < TE; ++e)
                hv[e] = *(const float4*)&H1[(ebase + e) * HS + 4 * c4];
            #pragma unroll
            for (int j = 0; j < 4; ++j) {
                const float* wr = &WbT[(4 * c4 + j) * 128 + og * 8];
                float4 wlo = *(const float4*)wr;
                float4 whi = *(const float4*)(wr + 4);
                #pragma unroll
                for (int e = 0; e < TE; ++e) {
                    float hc = (j == 0) ? hv[e].x : (j == 1) ? hv[e].y : (j == 2) ? hv[e].z : hv[e].w;
                    acc[e][0].x += hc * wlo.x; acc[e][0].y += hc * wlo.y;
                    acc[e][0].z += hc * wlo.z; acc[e][0].w += hc * wlo.w;
                    acc[e][1].x += hc * whi.x; acc[e][1].y += hc * whi.y;
                    acc[e][1].z += hc * whi.z; acc[e][1].w += hc * whi.w;
                }
            }
        }
        float4 mlo = lrelu4(acc[0][0]), mhi = lrelu4(acc[0][1]);
        #pragma unroll
        for (int e = 1; e < TE; ++e) {
            mlo = fmax4(mlo, lrelu4(acc[e][0]));
            mhi = fmax4(mhi, lrelu4(acc[e][1]));
        }
        if constexpr (K == 4) {
            float4* yp = (float4*)&yb[((size_t)(pt0 + eg)) * 128 + og * 8];
            yp[0] = mlo; yp[1] = mhi;
            __syncthreads();
        } else {
            *(float4*)&Pm[eg * 128 + og * 8] = mlo;
            *(float4*)&Pm[eg * 128 + og * 8 + 4] = mhi;
            __syncthreads();
            #pragma unroll
            for (int r = 0; r < 4; ++r) {
                int u = tid + r * NT;
                int p = u >> 7, o = u & 127;
                yb[((size_t)(pt0 + p)) * 128 + o] =
                    fmaxf(Pm[(2 * p) * 128 + o], Pm[(2 * p + 1) * 128 + o]);
            }
        }
    }
}

// ---------------- conv_mid: y -> x1 fp32 + sq1 + bf16 h/m/l split ----------------
__global__ void k_conv_mid(const float* __restrict__ xin, const float* __restrict__ W,
                           const float* __restrict__ bias, float* __restrict__ out,
                           float* __restrict__ sq, unsigned short* __restrict__ xh,
                           unsigned short* __restrict__ xm, unsigned short* __restrict__ xl) {
    int gid = blockIdx.x * blockDim.x + threadIdx.x;
    const float4* row = (const float4*)(xin + (size_t)gid * 128);
    float acc[32];
    #pragma unroll
    for (int o = 0; o < 32; ++o) acc[o] = bias[o];
    #pragma unroll 2
    for (int c4 = 0; c4 < 32; ++c4) {
        float4 v = row[c4];
        #pragma unroll
        for (int o = 0; o < 32; ++o) {
            const float* w = W + o * 128 + c4 * 4;   // uniform -> s_load
            acc[o] += v.x * w[0] + v.y * w[1] + v.z * w[2] + v.w * w[3];
        }
    }
    float s = 0.f;
    float4* op = (float4*)(out + (size_t)gid * 32);
    unsigned int* hrow = (unsigned int*)(xh + (size_t)gid * 32);
    unsigned int* mrow = (unsigned int*)(xm + (size_t)gid * 32);
    unsigned int* lrow = (unsigned int*)(xl + (size_t)gid * 32);
    #pragma unroll
    for (int o4 = 0; o4 < 8; ++o4) {
        float4 v = make_float4(lrelu(acc[o4 * 4]), lrelu(acc[o4 * 4 + 1]),
                               lrelu(acc[o4 * 4 + 2]), lrelu(acc[o4 * 4 + 3]));
        s += v.x * v.x + v.y * v.y + v.z * v.z + v.w * v.w;
        op[o4] = v;
        unsigned int hp[2], mp[2], lp[2];
        split3(v, hp, mp, lp);
        *(uint2*)(hrow + o4 * 2) = make_uint2(hp[0], hp[1]);
        *(uint2*)(mrow + o4 * 2) = make_uint2(mp[0], mp[1]);
        *(uint2*)(lrow + o4 * 2) = make_uint2(lp[0], lp[1]);
    }
    sq[gid] = s;
}

// ---------------- decoder: y1 [B*N,128] -> out [B*N,12] ----------------
__global__ void k_decoder(const float* __restrict__ xin,
                          const float* __restrict__ W0, const float* __restrict__ b0,
                          const float* __restrict__ W1, const float* __restrict__ b1,
                          const float* __restrict__ W2, const float* __restrict__ b2,
                          float* __restrict__ out) {
    int gid = blockIdx.x * blockDim.x + threadIdx.x;
    const float4* row = (const float4*)(xin + (size_t)gid * 128);
    float h0[6];
    #pragma unroll
    for (int o = 0; o < 6; ++o) h0[o] = b0[o];
    #pragma unroll 4
    for (int c4 = 0; c4 < 32; ++c4) {
        float4 v = row[c4];
        #pragma unroll
        for (int o = 0; o < 6; ++o) {
            const float* w = W0 + o * 128 + c4 * 4;
            h0[o] += v.x * w[0] + v.y * w[1] + v.z * w[2] + v.w * w[3];
        }
    }
    #pragma unroll
    for (int o = 0; o < 6; ++o) h0[o] = lrelu(h0[o]);
    float h1[12];
    #pragma unroll
    for (int o = 0; o < 12; ++o) {
        float a = b1[o];
        #pragma unroll
        for (int j = 0; j < 6; ++j) a += W1[o * 6 + j] * h0[j];
        h1[o] = lrelu(a);
    }
    float* op = out + (size_t)gid * 12;
    #pragma unroll
    for (int o = 0; o < 12; ++o) {
        float a = b2[o];
        #pragma unroll
        for (int j = 0; j < 12; ++j) a += W2[o * 12 + j] * h1[j];
        op[o] = a;
    }
}

extern "C" void kernel_launch(void* const* d_in, const int* in_sizes, int n_in,
                              void* d_out, int out_size, void* d_ws, size_t ws_size,
                              hipStream_t stream) {
    const float* feature = (const float*)d_in[0];
    const float* Wc0 = (const float*)d_in[1];
    const float* bc0 = (const float*)d_in[2];
    const float* We0a = (const float*)d_in[3];
    const float* be0a = (const float*)d_in[4];
    const float* We0b = (const float*)d_in[5];
    const float* be0b = (const float*)d_in[6];
    const float* Wc1 = (const float*)d_in[7];
    const float* bc1 = (const float*)d_in[8];
    const float* We1a = (const float*)d_in[9];
    const float* be1a = (const float*)d_in[10];
    const float* We1b = (const float*)d_in[11];
    const float* be1b = (const float*)d_in[12];
    const float* Wd0 = (const float*)d_in[13];
    const float* bd0 = (const float*)d_in[14];
    const float* Wd1 = (const float*)d_in[15];
    const float* bd1 = (const float*)d_in[16];
    const float* Wd2 = (const float*)d_in[17];
    const float* bd2 = (const float*)d_in[18];
    float* out = (float*)d_out;

    float* f = (float*)d_ws;
    // layout (floats), total ~30.7 MB with phase-based aliasing
    float* x0   = f;                       // [0, 524288)
    float* x1   = f + 524288;              // [524288, 1048576)
    int*   idx0 = (int*)(f + 1048576);     // 196608
    int*   idx1 = (int*)(f + 1245184);     // 65536
    float* wT   = f + 1310720;             // 32768 (WbT0 | WbT1)
    float* Zab  = f + 1343488;             // 4194304: A | Bm
    float* Abuf = Zab;                     // 2097152
    float* Bbuf = Zab + 2097152;           // 2097152
    float* Y    = f + 5537792;             // 2097152: y0, later y1
    float* sq0  = f + 7634944;             // 16384
    float* sq1  = f + 7651328;             // 16384 (end 7667712 ~ 30.7 MB)
    // cand0 aliases Zab (dead until premix): 8*16384*12 = 1572864 floats each
    float* c0d  = Zab;
    int*   c0i  = (int*)(Zab + 1572864);   // ends 3145728 < 4194304
    // xh0/xm0/xl0 alias Y (y0 written later by edgeconv): 262144 floats each
    unsigned short* xh0 = (unsigned short*)Y;
    unsigned short* xm0 = (unsigned short*)(Y + 262144);
    unsigned short* xl0 = (unsigned short*)(Y + 524288);
    // xh1/xm1/xl1 alias Zab (c0 dead after merge; premix1 writes A/B after knn<4>)
    unsigned short* xh1 = (unsigned short*)Zab;
    unsigned short* xm1 = (unsigned short*)(Zab + 262144);
    unsigned short* xl1 = (unsigned short*)(Zab + 524288);
    // cand1 aliases Y (y0 and splits dead by then): 524288 floats each
    float* c1d  = Y;
    int*   c1i  = (int*)(Y + 524288);      // ends 1048576 < 2097152
    float* WbT0 = wT;
    float* WbT1 = wT + 16384;

    k_transpose_w<<<128, 256, 0, stream>>>(We0b, We1b, wT);
    k_conv_in<<<64, 256, 0, stream>>>(feature, Wc0, bc0, x0, sq0, xh0, xm0, xl0);
    k_knn_mfma<12, 8, 12><<<512, 256, 0, stream>>>(xh0, xm0, xl0, sq0, c0d, c0i);
    k_knn_merge<12, 8><<<256, 64, 0, stream>>>(c0d, c0i, idx0);
    k_premix<<<256, 256, 0, stream>>>(x0, We0a, be0a, Abuf, Bbuf);
    k_edgeconv4<12><<<256, 256, 0, stream>>>(idx0, Abuf, Bbuf, WbT0, be0b, Y);
    k_conv_mid<<<64, 256, 0, stream>>>(Y, Wc1, bc1, x1, sq1, xh1, xm1, xl1);
    k_knn_mfma<4, 8, 8><<<512, 256, 0, stream>>>(xh1, xm1, xl1, sq1, c1d, c1i);
    k_knn_merge<4, 8><<<256, 64, 0, stream>>>(c1d, c1i, idx1);
    k_premix<<<256, 256, 0, stream>>>(x1, We1a, be1a, Abuf, Bbuf);
    k_edgeconv4<4><<<256, 256, 0, stream>>>(idx1, Abuf, Bbuf, WbT1, be1b, Y);
    k_decoder<<<64, 256, 0, stream>>>(Y, Wd0, bd0, Wd1, bd1, Wd2, bd2, out);
}